// Round 2
// baseline (1338.013 us; speedup 1.0000x reference)
//
#include <hip/hip_runtime.h>

// N=50000, E=800000, CUR=128, HID=96, OUT=128 (derived at runtime)

// ---------------------------------------------------------------------------
// bf16 helpers (manual, RNE)
__device__ __forceinline__ float bf2f(unsigned short u) {
    return __uint_as_float(((unsigned)u) << 16);
}
__device__ __forceinline__ unsigned short f2bf(float f) {
    unsigned u = __float_as_uint(f);
    return (unsigned short)((u + 0x7FFFu + ((u >> 16) & 1u)) >> 16);
}

// ---------------------------------------------------------------------------
// K0: detect int64 vs int32 edge_index (high words of first 1024 row-0
// entries all zero <=> int64). Deterministic.
__global__ void k_flag(const unsigned* __restrict__ ei, int* __restrict__ flag) {
    __shared__ int bad;
    if (threadIdx.x == 0) bad = 0;
    __syncthreads();
    unsigned w = ei[2 * threadIdx.x + 1];
    if (w != 0) atomicAdd(&bad, 1);
    __syncthreads();
    if (threadIdx.x == 0) *flag = (bad == 0) ? 1 : 0;  // 1 => int64
}

__device__ __forceinline__ int edge_src(const int* ei, int e, int E, int flag) {
    return flag ? ei[2 * e] : ei[e];
}
__device__ __forceinline__ int edge_dst(const int* ei, int e, int E, int flag) {
    return flag ? ei[2 * (E + e)] : ei[E + e];
}

// ---------------------------------------------------------------------------
// K1: xh = x @ pre_W + pre_b -> bf16 [N,96]. 16 nodes/block, 8 nodes/thread.
__global__ __launch_bounds__(192) void k_xh(const float* __restrict__ x,
                                            const float* __restrict__ W,
                                            const float* __restrict__ b,
                                            unsigned short* __restrict__ xhbf, int N) {
    __shared__ float xs[16][128];
    int t = threadIdx.x;
    int nb = blockIdx.x * 16;
    for (int u = t; u < 512; u += 192) {
        int node = u >> 5, q = u & 31;
        long gn = nb + node;
        float4 v = (gn < N) ? ((const float4*)(x + gn * 128))[q]
                            : make_float4(0.f, 0.f, 0.f, 0.f);
        *(float4*)&xs[node][q * 4] = v;
    }
    __syncthreads();
    int half = t / 96;
    int h = t - 96 * half;
    float acc[8];
#pragma unroll
    for (int i = 0; i < 8; i++) acc[i] = 0.f;
#pragma unroll
    for (int kk = 0; kk < 32; kk++) {
        float w0 = W[(4 * kk + 0) * 96 + h];
        float w1 = W[(4 * kk + 1) * 96 + h];
        float w2 = W[(4 * kk + 2) * 96 + h];
        float w3 = W[(4 * kk + 3) * 96 + h];
#pragma unroll
        for (int i = 0; i < 8; i++) {
            float4 xv = *(const float4*)&xs[half * 8 + i][kk * 4];
            acc[i] += xv.x * w0 + xv.y * w1 + xv.z * w2 + xv.w * w3;
        }
    }
    float bb = b[h];
#pragma unroll
    for (int i = 0; i < 8; i++) {
        long n = nb + half * 8 + i;
        if (n < N) xhbf[n * 96 + h] = f2bf(acc[i] + bb);
    }
}

// ---------------------------------------------------------------------------
// K2: per-edge degree / count (small atomics only)
__global__ void k_deg(const int* __restrict__ ei, const float* __restrict__ ew,
                      float* __restrict__ deg, float* __restrict__ cnt, int E,
                      const int* __restrict__ flagp) {
    int e = blockIdx.x * blockDim.x + threadIdx.x;
    if (e >= E) return;
    int flag = *flagp;
    int d = edge_dst(ei, e, E, flag);
    atomicAdd(&deg[d], ew[e]);
    atomicAdd(&cnt[d], 1.0f);
}

// K3: dinv (ARMA) and 1/max(cnt,1) (SAGE)
__global__ void k_dinv(const float* __restrict__ deg, const float* __restrict__ cnt,
                       float* __restrict__ dinv, float* __restrict__ minv, int N) {
    int n = blockIdx.x * blockDim.x + threadIdx.x;
    if (n >= N) return;
    float dg = deg[n];
    dinv[n] = dg > 0.f ? rsqrtf(fmaxf(dg, 1e-30f)) : 0.f;
    minv[n] = 1.f / fmaxf(cnt[n], 1.f);
}

// ---------------------------------------------------------------------------
// Prefix scan of cnt -> offs (3 kernels, Hillis-Steele per block)
__global__ void k_scan_blk(const float* __restrict__ cnt, int* __restrict__ offs,
                           int* __restrict__ bsum, int N) {
    __shared__ int sh[256];
    int t = threadIdx.x;
    int n = blockIdx.x * 256 + t;
    int v = (n < N) ? (int)cnt[n] : 0;
    sh[t] = v;
    __syncthreads();
    for (int off = 1; off < 256; off <<= 1) {
        int add = (t >= off) ? sh[t - off] : 0;
        __syncthreads();
        sh[t] += add;
        __syncthreads();
    }
    if (n < N) offs[n + 1] = sh[t];
    if (t == 255) bsum[blockIdx.x] = sh[255];
    if (blockIdx.x == 0 && t == 0) offs[0] = 0;
}

__global__ void k_scan_top(int* __restrict__ bsum, int nb) {
    __shared__ int sh[256];
    int t = threadIdx.x;
    sh[t] = (t < nb) ? bsum[t] : 0;
    __syncthreads();
    for (int off = 1; off < 256; off <<= 1) {
        int add = (t >= off) ? sh[t - off] : 0;
        __syncthreads();
        sh[t] += add;
        __syncthreads();
    }
    bsum[t] = sh[t];  // inclusive
}

__global__ void k_scan_add(int* __restrict__ offs, const int* __restrict__ bsum, int N) {
    int t = threadIdx.x;
    int n = blockIdx.x * 256 + t;
    if (n < N && blockIdx.x > 0) offs[n + 1] += bsum[blockIdx.x - 1];
}

// ---------------------------------------------------------------------------
// K4: fill CSR (dst-sorted edge arrays): esrc, wS=ew, wA=dinv[src]*ew
__global__ void k_fill(const int* __restrict__ ei, const float* __restrict__ ew,
                       const float* __restrict__ dinv, const int* __restrict__ offs,
                       int* __restrict__ cursor, int* __restrict__ esrc,
                       float* __restrict__ ewS, float* __restrict__ ewA, int E,
                       const int* __restrict__ flagp) {
    int e = blockIdx.x * blockDim.x + threadIdx.x;
    if (e >= E) return;
    int flag = *flagp;
    int s = edge_src(ei, e, E, flag);
    int d = edge_dst(ei, e, E, flag);
    int pos = atomicAdd(&cursor[d], 1);
    int idx = offs[d] + pos;
    float w = ew[e];
    esrc[idx] = s;
    ewS[idx] = w;
    ewA[idx] = dinv[s] * w;
}

// ---------------------------------------------------------------------------
// K5: gather per dst. 1 wave/dst; lanes 0..47 each own 2 feats (uint=2 bf16).
// Writes pre-scaled mean (x minv) and prop (x dinv) rows as bf16.
__global__ __launch_bounds__(256) void k_gather(
    const int* __restrict__ esrc, const float* __restrict__ ewS,
    const float* __restrict__ ewA, const unsigned short* __restrict__ xhbf,
    const int* __restrict__ offs, const float* __restrict__ dinv,
    const float* __restrict__ minv, unsigned short* __restrict__ meanbf,
    unsigned short* __restrict__ propbf, int N) {
    int lane = threadIdx.x & 63;
    int d = blockIdx.x * 4 + (threadIdx.x >> 6);
    if (d >= N) return;
    int beg = offs[d], end = offs[d + 1];
    bool act = lane < 48;
    float s0 = 0.f, s1 = 0.f, a0 = 0.f, a1 = 0.f;
    for (int e = beg; e < end; e++) {
        int s = esrc[e];
        float wS = ewS[e], wA = ewA[e];
        if (act) {
            unsigned v = *(const unsigned*)(xhbf + (size_t)s * 96 + 2 * lane);
            float x0 = bf2f((unsigned short)(v & 0xffff));
            float x1 = bf2f((unsigned short)(v >> 16));
            s0 += wS * x0; s1 += wS * x1;
            a0 += wA * x0; a1 += wA * x1;
        }
    }
    if (act) {
        float mi = minv[d], di = dinv[d];
        unsigned mo = (unsigned)f2bf(s0 * mi) | ((unsigned)f2bf(s1 * mi) << 16);
        unsigned po = (unsigned)f2bf(a0 * di) | ((unsigned)f2bf(a1 * di) << 16);
        *(unsigned*)(meanbf + (size_t)d * 96 + 2 * lane) = mo;
        *(unsigned*)(propbf + (size_t)d * 96 + 2 * lane) = po;
    }
}

// ---------------------------------------------------------------------------
// K6: epilogue. 16 nodes/block staged in LDS (bf16->f32), 8 nodes/thread,
// weights streamed coalesced and reused 8x.
__global__ __launch_bounds__(256) void k_out(
    const unsigned short* __restrict__ meanbf, const unsigned short* __restrict__ propbf,
    const unsigned short* __restrict__ xhbf, const float* __restrict__ Wl,
    const float* __restrict__ bl, const float* __restrict__ Wr,
    const float* __restrict__ Wa, const float* __restrict__ Va,
    const float* __restrict__ ba, float* __restrict__ out, int N) {
    __shared__ float A[3][16][96];
    int t = threadIdx.x;
    int nb = blockIdx.x * 16;
    const unsigned* pm = (const unsigned*)(meanbf + (size_t)nb * 96);
    const unsigned* pp = (const unsigned*)(propbf + (size_t)nb * 96);
    const unsigned* px = (const unsigned*)(xhbf + (size_t)nb * 96);
    for (int u = t; u < 2304; u += 256) {
        int arr = u / 768, rem = u - arr * 768;
        const unsigned* src = (arr == 0) ? pm : (arr == 1) ? pp : px;
        unsigned v = src[rem];
        int node = rem / 48, kp = rem - node * 48;
        A[arr][node][2 * kp] = bf2f((unsigned short)(v & 0xffff));
        A[arr][node][2 * kp + 1] = bf2f((unsigned short)(v >> 16));
    }
    __syncthreads();
    int j = t & 127, half = t >> 7;
    float aS[8], aA[8], aR[8], aV[8];
#pragma unroll
    for (int i = 0; i < 8; i++) { aS[i] = 0.f; aA[i] = 0.f; aR[i] = 0.f; aV[i] = 0.f; }
#pragma unroll
    for (int kk = 0; kk < 24; kk++) {
        float wl[4], wa[4], wr[4], va[4];
#pragma unroll
        for (int q = 0; q < 4; q++) {
            int k = 4 * kk + q;
            wl[q] = Wl[k * 128 + j];
            wa[q] = Wa[k * 128 + j];
            wr[q] = Wr[k * 128 + j];
            va[q] = Va[k * 128 + j];
        }
#pragma unroll
        for (int i = 0; i < 8; i++) {
            int node = half * 8 + i;
            float4 m = *(const float4*)&A[0][node][4 * kk];
            float4 p = *(const float4*)&A[1][node][4 * kk];
            float4 xv = *(const float4*)&A[2][node][4 * kk];
            aS[i] += m.x * wl[0] + m.y * wl[1] + m.z * wl[2] + m.w * wl[3];
            aA[i] += p.x * wa[0] + p.y * wa[1] + p.z * wa[2] + p.w * wa[3];
            aR[i] += xv.x * wr[0] + xv.y * wr[1] + xv.z * wr[2] + xv.w * wr[3];
            aV[i] += xv.x * va[0] + xv.y * va[1] + xv.z * va[2] + xv.w * va[3];
        }
    }
    float blj = bl[j], baj = ba[j];
#pragma unroll
    for (int i = 0; i < 8; i++) {
        long n = nb + half * 8 + i;
        if (n >= N) break;
        float os = aS[i] + blj + aR[i];
        float oa = fmaxf(aA[i] + aV[i] + baj, 0.f);
        float o1 = os > 0.f ? os : 0.01f * os;
        float o2 = oa > 0.f ? oa : 0.01f * oa;
        out[n * 128 + j] = fmaxf(o1 + o2, 0.f);
    }
}

// ---------------------------------------------------------------------------
extern "C" void kernel_launch(void* const* d_in, const int* in_sizes, int n_in,
                              void* d_out, int out_size, void* d_ws, size_t ws_size,
                              hipStream_t stream) {
    const float* x    = (const float*)d_in[1];
    const int*   ei   = (const int*)d_in[2];
    const float* ew   = (const float*)d_in[3];
    const float* preW = (const float*)d_in[4];
    const float* preb = (const float*)d_in[5];
    const float* Wl   = (const float*)d_in[6];
    const float* bl   = (const float*)d_in[7];
    const float* Wr   = (const float*)d_in[8];
    const float* Wa   = (const float*)d_in[9];
    const float* Va   = (const float*)d_in[10];
    const float* ba   = (const float*)d_in[11];

    const int N = in_sizes[1] / 128;
    const int E = in_sizes[3];
    const int NB = (N + 255) / 256;

    // ws layout
    char* w = (char*)d_ws;
    unsigned short* xhbf   = (unsigned short*)w; w += (size_t)N * 96 * 2;
    unsigned short* meanbf = (unsigned short*)w; w += (size_t)N * 96 * 2;
    unsigned short* propbf = (unsigned short*)w; w += (size_t)N * 96 * 2;
    int*   esrc = (int*)w;   w += (size_t)E * 4;
    float* ewS  = (float*)w; w += (size_t)E * 4;
    float* ewA  = (float*)w; w += (size_t)E * 4;
    float* deg  = (float*)w; w += (size_t)N * 4;
    float* cnt  = (float*)w; w += (size_t)N * 4;
    int*   cursor = (int*)w; w += (size_t)N * 4;
    float* dinv = (float*)w; w += (size_t)N * 4;
    float* minv = (float*)w; w += (size_t)N * 4;
    int*   offs = (int*)w;   w += (size_t)(N + 1) * 4;
    int*   bsum = (int*)w;   w += 256 * 4;
    int*   flag = (int*)w;

    // zero deg, cnt, cursor (contiguous)
    hipMemsetAsync(deg, 0, (size_t)N * 3 * 4, stream);

    k_flag<<<1, 1024, 0, stream>>>((const unsigned*)ei, flag);
    k_xh<<<(N + 15) / 16, 192, 0, stream>>>(x, preW, preb, xhbf, N);
    k_deg<<<(E + 255) / 256, 256, 0, stream>>>(ei, ew, deg, cnt, E, flag);
    k_dinv<<<NB, 256, 0, stream>>>(deg, cnt, dinv, minv, N);
    k_scan_blk<<<NB, 256, 0, stream>>>(cnt, offs, bsum, N);
    k_scan_top<<<1, 256, 0, stream>>>(bsum, NB);
    k_scan_add<<<NB, 256, 0, stream>>>(offs, bsum, N);
    k_fill<<<(E + 255) / 256, 256, 0, stream>>>(ei, ew, dinv, offs, cursor, esrc,
                                                ewS, ewA, E, flag);
    k_gather<<<(N + 3) / 4, 256, 0, stream>>>(esrc, ewS, ewA, xhbf, offs, dinv,
                                              minv, meanbf, propbf, N);
    // output 0: his = x
    hipMemcpyAsync(d_out, (void*)x, (size_t)N * 128 * sizeof(float),
                   hipMemcpyDeviceToDevice, stream);
    // output 1: o3
    k_out<<<(N + 15) / 16, 256, 0, stream>>>(meanbf, propbf, xhbf, Wl, bl, Wr, Wa,
                                             Va, ba, (float*)d_out + (size_t)N * 128, N);
}

// Round 3
// 413.424 us; speedup vs baseline: 3.2364x; 3.2364x over previous
//
#include <hip/hip_runtime.h>

// N=50000, E=800000, CUR=128, HID=96, OUT=128 (derived at runtime)

// ---------------------------------------------------------------------------
// bf16 helpers (manual, RNE)
__device__ __forceinline__ float bf2f(unsigned short u) {
    return __uint_as_float(((unsigned)u) << 16);
}
__device__ __forceinline__ unsigned short f2bf(float f) {
    unsigned u = __float_as_uint(f);
    return (unsigned short)((u + 0x7FFFu + ((u >> 16) & 1u)) >> 16);
}

// ---------------------------------------------------------------------------
// K0: detect int64 vs int32 edge_index (high words of first 1024 row-0
// entries all zero <=> int64). Deterministic.
__global__ void k_flag(const unsigned* __restrict__ ei, int* __restrict__ flag) {
    __shared__ int bad;
    if (threadIdx.x == 0) bad = 0;
    __syncthreads();
    unsigned w = ei[2 * threadIdx.x + 1];
    if (w != 0) atomicAdd(&bad, 1);
    __syncthreads();
    if (threadIdx.x == 0) *flag = (bad == 0) ? 1 : 0;  // 1 => int64
}

__device__ __forceinline__ int edge_src(const int* ei, int e, int E, int flag) {
    return flag ? ei[2 * e] : ei[e];
}
__device__ __forceinline__ int edge_dst(const int* ei, int e, int E, int flag) {
    return flag ? ei[2 * (E + e)] : ei[E + e];
}

// ---------------------------------------------------------------------------
// K1: xh = x @ pre_W + pre_b -> bf16 [N,96]. 16 nodes/block, 8 nodes/thread.
// unroll capped at 4: full unroll hoisted 128 W-loads -> 256 VGPR + spills (R2).
__global__ __launch_bounds__(192, 4) void k_xh(const float* __restrict__ x,
                                               const float* __restrict__ W,
                                               const float* __restrict__ b,
                                               unsigned short* __restrict__ xhbf, int N) {
    __shared__ float xs[16][128];
    int t = threadIdx.x;
    int nb = blockIdx.x * 16;
    for (int u = t; u < 512; u += 192) {
        int node = u >> 5, q = u & 31;
        long gn = nb + node;
        float4 v = (gn < N) ? ((const float4*)(x + gn * 128))[q]
                            : make_float4(0.f, 0.f, 0.f, 0.f);
        *(float4*)&xs[node][q * 4] = v;
    }
    __syncthreads();
    int half = t / 96;
    int h = t - 96 * half;
    float acc[8];
#pragma unroll
    for (int i = 0; i < 8; i++) acc[i] = 0.f;
#pragma unroll 4
    for (int kk = 0; kk < 32; kk++) {
        float w0 = W[(4 * kk + 0) * 96 + h];
        float w1 = W[(4 * kk + 1) * 96 + h];
        float w2 = W[(4 * kk + 2) * 96 + h];
        float w3 = W[(4 * kk + 3) * 96 + h];
#pragma unroll
        for (int i = 0; i < 8; i++) {
            float4 xv = *(const float4*)&xs[half * 8 + i][kk * 4];
            acc[i] += xv.x * w0 + xv.y * w1 + xv.z * w2 + xv.w * w3;
        }
    }
    float bb = b[h];
#pragma unroll
    for (int i = 0; i < 8; i++) {
        long n = nb + half * 8 + i;
        if (n < N) xhbf[n * 96 + h] = f2bf(acc[i] + bb);
    }
}

// ---------------------------------------------------------------------------
// K2: per-edge degree / count (small atomics only)
__global__ void k_deg(const int* __restrict__ ei, const float* __restrict__ ew,
                      float* __restrict__ deg, float* __restrict__ cnt, int E,
                      const int* __restrict__ flagp) {
    int e = blockIdx.x * blockDim.x + threadIdx.x;
    if (e >= E) return;
    int flag = *flagp;
    int d = edge_dst(ei, e, E, flag);
    atomicAdd(&deg[d], ew[e]);
    atomicAdd(&cnt[d], 1.0f);
}

// K3: dinv (ARMA) and 1/max(cnt,1) (SAGE)
__global__ void k_dinv(const float* __restrict__ deg, const float* __restrict__ cnt,
                       float* __restrict__ dinv, float* __restrict__ minv, int N) {
    int n = blockIdx.x * blockDim.x + threadIdx.x;
    if (n >= N) return;
    float dg = deg[n];
    dinv[n] = dg > 0.f ? rsqrtf(fmaxf(dg, 1e-30f)) : 0.f;
    minv[n] = 1.f / fmaxf(cnt[n], 1.f);
}

// ---------------------------------------------------------------------------
// Prefix scan of cnt -> offs (3 kernels, Hillis-Steele per block)
__global__ void k_scan_blk(const float* __restrict__ cnt, int* __restrict__ offs,
                           int* __restrict__ bsum, int N) {
    __shared__ int sh[256];
    int t = threadIdx.x;
    int n = blockIdx.x * 256 + t;
    int v = (n < N) ? (int)cnt[n] : 0;
    sh[t] = v;
    __syncthreads();
    for (int off = 1; off < 256; off <<= 1) {
        int add = (t >= off) ? sh[t - off] : 0;
        __syncthreads();
        sh[t] += add;
        __syncthreads();
    }
    if (n < N) offs[n + 1] = sh[t];
    if (t == 255) bsum[blockIdx.x] = sh[255];
    if (blockIdx.x == 0 && t == 0) offs[0] = 0;
}

__global__ void k_scan_top(int* __restrict__ bsum, int nb) {
    __shared__ int sh[256];
    int t = threadIdx.x;
    sh[t] = (t < nb) ? bsum[t] : 0;
    __syncthreads();
    for (int off = 1; off < 256; off <<= 1) {
        int add = (t >= off) ? sh[t - off] : 0;
        __syncthreads();
        sh[t] += add;
        __syncthreads();
    }
    bsum[t] = sh[t];  // inclusive
}

__global__ void k_scan_add(int* __restrict__ offs, const int* __restrict__ bsum, int N) {
    int t = threadIdx.x;
    int n = blockIdx.x * 256 + t;
    if (n < N && blockIdx.x > 0) offs[n + 1] += bsum[blockIdx.x - 1];
}

// ---------------------------------------------------------------------------
// K4: fill CSR (dst-sorted edge arrays): esrc, wS=ew, wA=dinv[src]*ew
__global__ void k_fill(const int* __restrict__ ei, const float* __restrict__ ew,
                       const float* __restrict__ dinv, const int* __restrict__ offs,
                       int* __restrict__ cursor, int* __restrict__ esrc,
                       float* __restrict__ ewS, float* __restrict__ ewA, int E,
                       const int* __restrict__ flagp) {
    int e = blockIdx.x * blockDim.x + threadIdx.x;
    if (e >= E) return;
    int flag = *flagp;
    int s = edge_src(ei, e, E, flag);
    int d = edge_dst(ei, e, E, flag);
    int pos = atomicAdd(&cursor[d], 1);
    int idx = offs[d] + pos;
    float w = ew[e];
    esrc[idx] = s;
    ewS[idx] = w;
    ewA[idx] = dinv[s] * w;
}

// ---------------------------------------------------------------------------
// K5: gather per dst. 1 wave/dst; lanes 0..47 each own 2 feats (uint=2 bf16).
// Writes pre-scaled mean (x minv) and prop (x dinv) rows as bf16.
__global__ __launch_bounds__(256) void k_gather(
    const int* __restrict__ esrc, const float* __restrict__ ewS,
    const float* __restrict__ ewA, const unsigned short* __restrict__ xhbf,
    const int* __restrict__ offs, const float* __restrict__ dinv,
    const float* __restrict__ minv, unsigned short* __restrict__ meanbf,
    unsigned short* __restrict__ propbf, int N) {
    int lane = threadIdx.x & 63;
    int d = blockIdx.x * 4 + (threadIdx.x >> 6);
    if (d >= N) return;
    int beg = offs[d], end = offs[d + 1];
    bool act = lane < 48;
    float s0 = 0.f, s1 = 0.f, a0 = 0.f, a1 = 0.f;
    for (int e = beg; e < end; e++) {
        int s = esrc[e];
        float wS = ewS[e], wA = ewA[e];
        if (act) {
            unsigned v = *(const unsigned*)(xhbf + (size_t)s * 96 + 2 * lane);
            float x0 = bf2f((unsigned short)(v & 0xffff));
            float x1 = bf2f((unsigned short)(v >> 16));
            s0 += wS * x0; s1 += wS * x1;
            a0 += wA * x0; a1 += wA * x1;
        }
    }
    if (act) {
        float mi = minv[d], di = dinv[d];
        unsigned mo = (unsigned)f2bf(s0 * mi) | ((unsigned)f2bf(s1 * mi) << 16);
        unsigned po = (unsigned)f2bf(a0 * di) | ((unsigned)f2bf(a1 * di) << 16);
        *(unsigned*)(meanbf + (size_t)d * 96 + 2 * lane) = mo;
        *(unsigned*)(propbf + (size_t)d * 96 + 2 * lane) = po;
    }
}

// ---------------------------------------------------------------------------
// K6: epilogue. 16 nodes/block staged in LDS (bf16->f32), 8 nodes/thread,
// weights streamed coalesced and reused 8x. unroll capped at 2 (384 hoistable
// W-loads at full unroll -> spills, cf. R2's k_xh).
__global__ __launch_bounds__(256, 4) void k_out(
    const unsigned short* __restrict__ meanbf, const unsigned short* __restrict__ propbf,
    const unsigned short* __restrict__ xhbf, const float* __restrict__ Wl,
    const float* __restrict__ bl, const float* __restrict__ Wr,
    const float* __restrict__ Wa, const float* __restrict__ Va,
    const float* __restrict__ ba, float* __restrict__ out, int N) {
    __shared__ float A[3][16][96];
    int t = threadIdx.x;
    int nb = blockIdx.x * 16;
    const unsigned* pm = (const unsigned*)(meanbf + (size_t)nb * 96);
    const unsigned* pp = (const unsigned*)(propbf + (size_t)nb * 96);
    const unsigned* px = (const unsigned*)(xhbf + (size_t)nb * 96);
    for (int u = t; u < 2304; u += 256) {
        int arr = u / 768, rem = u - arr * 768;
        const unsigned* src = (arr == 0) ? pm : (arr == 1) ? pp : px;
        unsigned v = src[rem];
        int node = rem / 48, kp = rem - node * 48;
        A[arr][node][2 * kp] = bf2f((unsigned short)(v & 0xffff));
        A[arr][node][2 * kp + 1] = bf2f((unsigned short)(v >> 16));
    }
    __syncthreads();
    int j = t & 127, half = t >> 7;
    float aS[8], aA[8], aR[8], aV[8];
#pragma unroll
    for (int i = 0; i < 8; i++) { aS[i] = 0.f; aA[i] = 0.f; aR[i] = 0.f; aV[i] = 0.f; }
#pragma unroll 2
    for (int kk = 0; kk < 24; kk++) {
        float wl[4], wa[4], wr[4], va[4];
#pragma unroll
        for (int q = 0; q < 4; q++) {
            int k = 4 * kk + q;
            wl[q] = Wl[k * 128 + j];
            wa[q] = Wa[k * 128 + j];
            wr[q] = Wr[k * 128 + j];
            va[q] = Va[k * 128 + j];
        }
#pragma unroll
        for (int i = 0; i < 8; i++) {
            int node = half * 8 + i;
            float4 m = *(const float4*)&A[0][node][4 * kk];
            float4 p = *(const float4*)&A[1][node][4 * kk];
            float4 xv = *(const float4*)&A[2][node][4 * kk];
            aS[i] += m.x * wl[0] + m.y * wl[1] + m.z * wl[2] + m.w * wl[3];
            aA[i] += p.x * wa[0] + p.y * wa[1] + p.z * wa[2] + p.w * wa[3];
            aR[i] += xv.x * wr[0] + xv.y * wr[1] + xv.z * wr[2] + xv.w * wr[3];
            aV[i] += xv.x * va[0] + xv.y * va[1] + xv.z * va[2] + xv.w * va[3];
        }
    }
    float blj = bl[j], baj = ba[j];
#pragma unroll
    for (int i = 0; i < 8; i++) {
        long n = nb + half * 8 + i;
        if (n >= N) break;
        float os = aS[i] + blj + aR[i];
        float oa = fmaxf(aA[i] + aV[i] + baj, 0.f);
        float o1 = os > 0.f ? os : 0.01f * os;
        float o2 = oa > 0.f ? oa : 0.01f * oa;
        out[n * 128 + j] = fmaxf(o1 + o2, 0.f);
    }
}

// ---------------------------------------------------------------------------
extern "C" void kernel_launch(void* const* d_in, const int* in_sizes, int n_in,
                              void* d_out, int out_size, void* d_ws, size_t ws_size,
                              hipStream_t stream) {
    const float* x    = (const float*)d_in[1];
    const int*   ei   = (const int*)d_in[2];
    const float* ew   = (const float*)d_in[3];
    const float* preW = (const float*)d_in[4];
    const float* preb = (const float*)d_in[5];
    const float* Wl   = (const float*)d_in[6];
    const float* bl   = (const float*)d_in[7];
    const float* Wr   = (const float*)d_in[8];
    const float* Wa   = (const float*)d_in[9];
    const float* Va   = (const float*)d_in[10];
    const float* ba   = (const float*)d_in[11];

    const int N = in_sizes[1] / 128;
    const int E = in_sizes[3];
    const int NB = (N + 255) / 256;

    // ws layout
    char* w = (char*)d_ws;
    unsigned short* xhbf   = (unsigned short*)w; w += (size_t)N * 96 * 2;
    unsigned short* meanbf = (unsigned short*)w; w += (size_t)N * 96 * 2;
    unsigned short* propbf = (unsigned short*)w; w += (size_t)N * 96 * 2;
    int*   esrc = (int*)w;   w += (size_t)E * 4;
    float* ewS  = (float*)w; w += (size_t)E * 4;
    float* ewA  = (float*)w; w += (size_t)E * 4;
    float* deg  = (float*)w; w += (size_t)N * 4;
    float* cnt  = (float*)w; w += (size_t)N * 4;
    int*   cursor = (int*)w; w += (size_t)N * 4;
    float* dinv = (float*)w; w += (size_t)N * 4;
    float* minv = (float*)w; w += (size_t)N * 4;
    int*   offs = (int*)w;   w += (size_t)(N + 1) * 4;
    int*   bsum = (int*)w;   w += 256 * 4;
    int*   flag = (int*)w;

    // zero deg, cnt, cursor (contiguous)
    hipMemsetAsync(deg, 0, (size_t)N * 3 * 4, stream);

    k_flag<<<1, 1024, 0, stream>>>((const unsigned*)ei, flag);
    k_xh<<<(N + 15) / 16, 192, 0, stream>>>(x, preW, preb, xhbf, N);
    k_deg<<<(E + 255) / 256, 256, 0, stream>>>(ei, ew, deg, cnt, E, flag);
    k_dinv<<<NB, 256, 0, stream>>>(deg, cnt, dinv, minv, N);
    k_scan_blk<<<NB, 256, 0, stream>>>(cnt, offs, bsum, N);
    k_scan_top<<<1, 256, 0, stream>>>(bsum, NB);
    k_scan_add<<<NB, 256, 0, stream>>>(offs, bsum, N);
    k_fill<<<(E + 255) / 256, 256, 0, stream>>>(ei, ew, dinv, offs, cursor, esrc,
                                                ewS, ewA, E, flag);
    k_gather<<<(N + 3) / 4, 256, 0, stream>>>(esrc, ewS, ewA, xhbf, offs, dinv,
                                              minv, meanbf, propbf, N);
    // output 0: his = x
    hipMemcpyAsync(d_out, (void*)x, (size_t)N * 128 * sizeof(float),
                   hipMemcpyDeviceToDevice, stream);
    // output 1: o3
    k_out<<<(N + 15) / 16, 256, 0, stream>>>(meanbf, propbf, xhbf, Wl, bl, Wr, Wa,
                                             Va, ba, (float*)d_out + (size_t)N * 128, N);
}

// Round 4
// 282.630 us; speedup vs baseline: 4.7342x; 1.4628x over previous
//
#include <hip/hip_runtime.h>

// N=50000, E=800000, CUR=128, HID=96, OUT=128 (derived at runtime)

typedef __attribute__((ext_vector_type(8))) short bf16x8;   // MFMA A/B frag
typedef __attribute__((ext_vector_type(4))) float f32x4;    // MFMA C/D frag

// ---------------------------------------------------------------------------
__device__ __forceinline__ float bf2f(unsigned short u) {
    return __uint_as_float(((unsigned)u) << 16);
}
__device__ __forceinline__ unsigned short f2bf(float f) {
    unsigned u = __float_as_uint(f);
    return (unsigned short)((u + 0x7FFFu + ((u >> 16) & 1u)) >> 16);
}

// ---------------------------------------------------------------------------
// K0: detect int64 vs int32 edge_index. Deterministic.
__global__ void k_flag(const unsigned* __restrict__ ei, int* __restrict__ flag) {
    __shared__ int bad;
    if (threadIdx.x == 0) bad = 0;
    __syncthreads();
    unsigned w = ei[2 * threadIdx.x + 1];
    if (w != 0) atomicAdd(&bad, 1);
    __syncthreads();
    if (threadIdx.x == 0) *flag = (bad == 0) ? 1 : 0;  // 1 => int64
}

__device__ __forceinline__ int edge_src(const int* ei, int e, int E, int flag) {
    return flag ? ei[2 * e] : ei[e];
}
__device__ __forceinline__ int edge_dst(const int* ei, int e, int E, int flag) {
    return flag ? ei[2 * (E + e)] : ei[E + e];
}

// ---------------------------------------------------------------------------
// Weight repack into MFMA-B-fragment-contiguous layout:
//   Wf[(kstep*4+g)*ncol + j][0..7] holds k = kstep*32 + g*8 + kk, col j (bf16)
// Wf_s from [Wl;Wr] (K=192,ncol=128), Wf_a from [Wa;Va], Wfp from pre_W (K=128,ncol=96)
__global__ void k_wprep(const float* __restrict__ Wl, const float* __restrict__ Wr,
                        const float* __restrict__ Wa, const float* __restrict__ Va,
                        const float* __restrict__ preW,
                        unsigned short* __restrict__ Wf_s,
                        unsigned short* __restrict__ Wf_a,
                        unsigned short* __restrict__ Wfp) {
    int tid = blockIdx.x * blockDim.x + threadIdx.x;
    if (tid < 6144) {  // main weights: 2 mats x 6 ksteps x 4 g x 128 j
        int mat = tid / 3072, rem = tid % 3072;
        int kstep = rem / 512, rem2 = rem % 512;
        int g = rem2 / 128, j = rem2 % 128;
        int k0 = kstep * 32 + g * 8;
        const float* Wtop = mat ? Wa : Wl;
        const float* Wbot = mat ? Va : Wr;
        unsigned short* dst = (mat ? Wf_a : Wf_s) + (((size_t)(kstep * 4 + g) * 128 + j) * 8);
#pragma unroll
        for (int kk = 0; kk < 8; kk++) {
            int k = k0 + kk;
            float v = (k < 96) ? Wtop[k * 128 + j] : Wbot[(k - 96) * 128 + j];
            dst[kk] = f2bf(v);
        }
    } else if (tid < 7680) {  // pre weights: 4 ksteps x 4 g x 96 j
        int rem = tid - 6144;
        int kstep = rem / 384, rem2 = rem % 384;
        int g = rem2 / 96, j = rem2 % 96;
        int k0 = kstep * 32 + g * 8;
        unsigned short* dst = Wfp + (((size_t)(kstep * 4 + g) * 96 + j) * 8);
#pragma unroll
        for (int kk = 0; kk < 8; kk++) dst[kk] = f2bf(preW[(k0 + kk) * 96 + j]);
    }
}

// ---------------------------------------------------------------------------
// K1: xh = x @ pre_W + pre_b -> bf16 [N,96], MFMA 16x16x32. 64 nodes/block.
__global__ __launch_bounds__(256) void k_xh(const float* __restrict__ x,
                                            const unsigned short* __restrict__ Wfp,
                                            const float* __restrict__ b,
                                            unsigned short* __restrict__ xhbf, int N) {
    __shared__ unsigned short X[64][136];  // pad 136 shorts = 17x16B (odd) => 2-way max
    int t = threadIdx.x;
    int nb = blockIdx.x * 64;
    // stage x (f32 -> bf16): 64 rows x 32 float4
    for (int u = t; u < 2048; u += 256) {
        int row = u >> 5, q = u & 31;
        long gn = nb + row;
        float4 v = (gn < N) ? ((const float4*)(x + gn * 128))[q]
                            : make_float4(0.f, 0.f, 0.f, 0.f);
        unsigned short* p = &X[row][q * 4];
        p[0] = f2bf(v.x); p[1] = f2bf(v.y); p[2] = f2bf(v.z); p[3] = f2bf(v.w);
    }
    __syncthreads();
    int lane = t & 63, w = t >> 6;
    int lr = lane & 15, lg = lane >> 4;  // frag row/col and k-group
    // A fragments: 4 ksteps (K=128)
    bf16x8 a[4];
#pragma unroll
    for (int ks = 0; ks < 4; ks++)
        a[ks] = *(const bf16x8*)&X[w * 16 + lr][ks * 32 + lg * 8];
    // 6 j-tiles of 16 (HID=96)
    for (int jt = 0; jt < 6; jt++) {
        f32x4 acc = {0.f, 0.f, 0.f, 0.f};
#pragma unroll
        for (int ks = 0; ks < 4; ks++) {
            bf16x8 bf = *(const bf16x8*)(Wfp + (((size_t)(ks * 4 + lg) * 96 + jt * 16 + lr) * 8));
            acc = __builtin_amdgcn_mfma_f32_16x16x32_bf16(a[ks], bf, acc, 0, 0, 0);
        }
        int h = jt * 16 + lr;
        float bb = b[h];
#pragma unroll
        for (int r = 0; r < 4; r++) {
            long n = nb + w * 16 + lg * 4 + r;
            if (n < N) xhbf[n * 96 + h] = f2bf(acc[r] + bb);
        }
    }
}

// ---------------------------------------------------------------------------
// K2: per-edge degree / count
__global__ void k_deg(const int* __restrict__ ei, const float* __restrict__ ew,
                      float* __restrict__ deg, float* __restrict__ cnt, int E,
                      const int* __restrict__ flagp) {
    int e = blockIdx.x * blockDim.x + threadIdx.x;
    if (e >= E) return;
    int flag = *flagp;
    int d = edge_dst(ei, e, E, flag);
    atomicAdd(&deg[d], ew[e]);
    atomicAdd(&cnt[d], 1.0f);
}

// K3: dinv (ARMA) and 1/max(cnt,1) (SAGE)
__global__ void k_dinv(const float* __restrict__ deg, const float* __restrict__ cnt,
                       float* __restrict__ dinv, float* __restrict__ minv, int N) {
    int n = blockIdx.x * blockDim.x + threadIdx.x;
    if (n >= N) return;
    float dg = deg[n];
    dinv[n] = dg > 0.f ? rsqrtf(fmaxf(dg, 1e-30f)) : 0.f;
    minv[n] = 1.f / fmaxf(cnt[n], 1.f);
}

// ---------------------------------------------------------------------------
// Prefix scan of cnt -> offs
__global__ void k_scan_blk(const float* __restrict__ cnt, int* __restrict__ offs,
                           int* __restrict__ bsum, int N) {
    __shared__ int sh[256];
    int t = threadIdx.x;
    int n = blockIdx.x * 256 + t;
    int v = (n < N) ? (int)cnt[n] : 0;
    sh[t] = v;
    __syncthreads();
    for (int off = 1; off < 256; off <<= 1) {
        int add = (t >= off) ? sh[t - off] : 0;
        __syncthreads();
        sh[t] += add;
        __syncthreads();
    }
    if (n < N) offs[n + 1] = sh[t];
    if (t == 255) bsum[blockIdx.x] = sh[255];
    if (blockIdx.x == 0 && t == 0) offs[0] = 0;
}

__global__ void k_scan_top(int* __restrict__ bsum, int nb) {
    __shared__ int sh[256];
    int t = threadIdx.x;
    sh[t] = (t < nb) ? bsum[t] : 0;
    __syncthreads();
    for (int off = 1; off < 256; off <<= 1) {
        int add = (t >= off) ? sh[t - off] : 0;
        __syncthreads();
        sh[t] += add;
        __syncthreads();
    }
    bsum[t] = sh[t];
}

__global__ void k_scan_add(int* __restrict__ offs, const int* __restrict__ bsum, int N) {
    int t = threadIdx.x;
    int n = blockIdx.x * 256 + t;
    if (n < N && blockIdx.x > 0) offs[n + 1] += bsum[blockIdx.x - 1];
}

// ---------------------------------------------------------------------------
// K4: fill CSR: esrc, ewS=ew, ewA=dinv[src]*ew
__global__ void k_fill(const int* __restrict__ ei, const float* __restrict__ ew,
                       const float* __restrict__ dinv, const int* __restrict__ offs,
                       int* __restrict__ cursor, int* __restrict__ esrc,
                       float* __restrict__ ewS, float* __restrict__ ewA, int E,
                       const int* __restrict__ flagp) {
    int e = blockIdx.x * blockDim.x + threadIdx.x;
    if (e >= E) return;
    int flag = *flagp;
    int s = edge_src(ei, e, E, flag);
    int d = edge_dst(ei, e, E, flag);
    int pos = atomicAdd(&cursor[d], 1);
    int idx = offs[d] + pos;
    float w = ew[e];
    esrc[idx] = s;
    ewS[idx] = w;
    ewA[idx] = dinv[s] * w;
}

// ---------------------------------------------------------------------------
// K5: gather per dst (1 wave/dst), writes pre-scaled mean/prop rows bf16.
__global__ __launch_bounds__(256) void k_gather(
    const int* __restrict__ esrc, const float* __restrict__ ewS,
    const float* __restrict__ ewA, const unsigned short* __restrict__ xhbf,
    const int* __restrict__ offs, const float* __restrict__ dinv,
    const float* __restrict__ minv, unsigned short* __restrict__ meanbf,
    unsigned short* __restrict__ propbf, int N) {
    int lane = threadIdx.x & 63;
    int d = blockIdx.x * 4 + (threadIdx.x >> 6);
    if (d >= N) return;
    int beg = offs[d], end = offs[d + 1];
    bool act = lane < 48;
    float s0 = 0.f, s1 = 0.f, a0 = 0.f, a1 = 0.f;
    for (int e = beg; e < end; e++) {
        int s = esrc[e];
        float wS = ewS[e], wA = ewA[e];
        if (act) {
            unsigned v = *(const unsigned*)(xhbf + (size_t)s * 96 + 2 * lane);
            float x0 = bf2f((unsigned short)(v & 0xffff));
            float x1 = bf2f((unsigned short)(v >> 16));
            s0 += wS * x0; s1 += wS * x1;
            a0 += wA * x0; a1 += wA * x1;
        }
    }
    if (act) {
        float mi = minv[d], di = dinv[d];
        unsigned mo = (unsigned)f2bf(s0 * mi) | ((unsigned)f2bf(s1 * mi) << 16);
        unsigned po = (unsigned)f2bf(a0 * di) | ((unsigned)f2bf(a1 * di) << 16);
        *(unsigned*)(meanbf + (size_t)d * 96 + 2 * lane) = mo;
        *(unsigned*)(propbf + (size_t)d * 96 + 2 * lane) = po;
    }
}

// ---------------------------------------------------------------------------
// K6: epilogue via two K=192 MFMA GEMMs: o_sage=[mean|xh]@[Wl;Wr]+bl,
// o_arma=relu([prop|xh]@[Wa;Va]+ba); combine leaky+relu. 64 nodes/block.
__global__ __launch_bounds__(256) void k_out(
    const unsigned short* __restrict__ meanbf, const unsigned short* __restrict__ propbf,
    const unsigned short* __restrict__ xhbf, const unsigned short* __restrict__ Wf_s,
    const unsigned short* __restrict__ Wf_a, const float* __restrict__ bl,
    const float* __restrict__ ba, float* __restrict__ out, int N) {
    __shared__ unsigned short A[3][64][104];  // 104 shorts = 13x16B (odd) => 2-way max
    int t = threadIdx.x;
    int nb = blockIdx.x * 64;
    // stage mean/prop/xh: 3 arrays x 64 rows x 12 float4 (96 shorts)
    for (int u = t; u < 2304; u += 256) {
        int arr = u / 768, rem = u - arr * 768;
        int row = rem / 12, c = rem - row * 12;
        long gn = nb + row;
        const unsigned short* src = (arr == 0) ? meanbf : (arr == 1) ? propbf : xhbf;
        float4 v = (gn < N) ? *(const float4*)(src + gn * 96 + c * 8)
                            : make_float4(0.f, 0.f, 0.f, 0.f);
        *(float4*)&A[arr][row][c * 8] = v;
    }
    __syncthreads();
    int lane = t & 63, w = t >> 6;
    int lr = lane & 15, lg = lane >> 4;
    // A fragments: mean[3], prop[3], xh[3] ksteps
    bf16x8 am[3], ap[3], ax[3];
#pragma unroll
    for (int ks = 0; ks < 3; ks++) {
        int row = w * 16 + lr, kc = ks * 32 + lg * 8;
        am[ks] = *(const bf16x8*)&A[0][row][kc];
        ap[ks] = *(const bf16x8*)&A[1][row][kc];
        ax[ks] = *(const bf16x8*)&A[2][row][kc];
    }
    for (int jt = 0; jt < 8; jt++) {
        f32x4 accS = {0.f, 0.f, 0.f, 0.f};
        f32x4 accA = {0.f, 0.f, 0.f, 0.f};
#pragma unroll
        for (int ks = 0; ks < 3; ks++) {
            size_t boffS = ((size_t)(ks * 4 + lg) * 128 + jt * 16 + lr) * 8;
            size_t boffS2 = ((size_t)((ks + 3) * 4 + lg) * 128 + jt * 16 + lr) * 8;
            bf16x8 b0 = *(const bf16x8*)(Wf_s + boffS);
            bf16x8 b1 = *(const bf16x8*)(Wf_s + boffS2);
            bf16x8 b2 = *(const bf16x8*)(Wf_a + boffS);
            bf16x8 b3 = *(const bf16x8*)(Wf_a + boffS2);
            accS = __builtin_amdgcn_mfma_f32_16x16x32_bf16(am[ks], b0, accS, 0, 0, 0);
            accS = __builtin_amdgcn_mfma_f32_16x16x32_bf16(ax[ks], b1, accS, 0, 0, 0);
            accA = __builtin_amdgcn_mfma_f32_16x16x32_bf16(ap[ks], b2, accA, 0, 0, 0);
            accA = __builtin_amdgcn_mfma_f32_16x16x32_bf16(ax[ks], b3, accA, 0, 0, 0);
        }
        int j = jt * 16 + lr;
        float blj = bl[j], baj = ba[j];
#pragma unroll
        for (int r = 0; r < 4; r++) {
            long n = nb + w * 16 + lg * 4 + r;
            if (n < N) {
                float os = accS[r] + blj;
                float oa = fmaxf(accA[r] + baj, 0.f);
                float o1 = os > 0.f ? os : 0.01f * os;
                float o2 = oa > 0.f ? oa : 0.01f * oa;
                out[n * 128 + j] = fmaxf(o1 + o2, 0.f);
            }
        }
    }
}

// ---------------------------------------------------------------------------
extern "C" void kernel_launch(void* const* d_in, const int* in_sizes, int n_in,
                              void* d_out, int out_size, void* d_ws, size_t ws_size,
                              hipStream_t stream) {
    const float* x    = (const float*)d_in[1];
    const int*   ei   = (const int*)d_in[2];
    const float* ew   = (const float*)d_in[3];
    const float* preW = (const float*)d_in[4];
    const float* preb = (const float*)d_in[5];
    const float* Wl   = (const float*)d_in[6];
    const float* bl   = (const float*)d_in[7];
    const float* Wr   = (const float*)d_in[8];
    const float* Wa   = (const float*)d_in[9];
    const float* Va   = (const float*)d_in[10];
    const float* ba   = (const float*)d_in[11];

    const int N = in_sizes[1] / 128;
    const int E = in_sizes[3];
    const int NB = (N + 255) / 256;

    // ws layout
    char* w = (char*)d_ws;
    unsigned short* xhbf   = (unsigned short*)w; w += (size_t)N * 96 * 2;
    unsigned short* meanbf = (unsigned short*)w; w += (size_t)N * 96 * 2;
    unsigned short* propbf = (unsigned short*)w; w += (size_t)N * 96 * 2;
    unsigned short* Wf_s   = (unsigned short*)w; w += (size_t)6 * 4 * 128 * 8 * 2;
    unsigned short* Wf_a   = (unsigned short*)w; w += (size_t)6 * 4 * 128 * 8 * 2;
    unsigned short* Wfp    = (unsigned short*)w; w += (size_t)4 * 4 * 96 * 8 * 2;
    int*   esrc = (int*)w;   w += (size_t)E * 4;
    float* ewS  = (float*)w; w += (size_t)E * 4;
    float* ewA  = (float*)w; w += (size_t)E * 4;
    float* deg  = (float*)w; w += (size_t)N * 4;
    float* cnt  = (float*)w; w += (size_t)N * 4;
    int*   cursor = (int*)w; w += (size_t)N * 4;
    float* dinv = (float*)w; w += (size_t)N * 4;
    float* minv = (float*)w; w += (size_t)N * 4;
    int*   offs = (int*)w;   w += (size_t)(N + 1) * 4;
    int*   bsum = (int*)w;   w += 256 * 4;
    int*   flag = (int*)w;

    // zero deg, cnt, cursor (contiguous)
    hipMemsetAsync(deg, 0, (size_t)N * 3 * 4, stream);

    k_flag<<<1, 1024, 0, stream>>>((const unsigned*)ei, flag);
    k_wprep<<<30, 256, 0, stream>>>(Wl, Wr, Wa, Va, preW, Wf_s, Wf_a, Wfp);
    k_xh<<<(N + 63) / 64, 256, 0, stream>>>(x, Wfp, preb, xhbf, N);
    k_deg<<<(E + 255) / 256, 256, 0, stream>>>(ei, ew, deg, cnt, E, flag);
    k_dinv<<<NB, 256, 0, stream>>>(deg, cnt, dinv, minv, N);
    k_scan_blk<<<NB, 256, 0, stream>>>(cnt, offs, bsum, N);
    k_scan_top<<<1, 256, 0, stream>>>(bsum, NB);
    k_scan_add<<<NB, 256, 0, stream>>>(offs, bsum, N);
    k_fill<<<(E + 255) / 256, 256, 0, stream>>>(ei, ew, dinv, offs, cursor, esrc,
                                                ewS, ewA, E, flag);
    k_gather<<<(N + 3) / 4, 256, 0, stream>>>(esrc, ewS, ewA, xhbf, offs, dinv,
                                              minv, meanbf, propbf, N);
    // output 0: his = x
    hipMemcpyAsync(d_out, (void*)x, (size_t)N * 128 * sizeof(float),
                   hipMemcpyDeviceToDevice, stream);
    // output 1: o3
    k_out<<<(N + 63) / 64, 256, 0, stream>>>(meanbf, propbf, xhbf, Wf_s, Wf_a,
                                             bl, ba, (float*)d_out + (size_t)N * 128, N);
}

// Round 5
// 231.054 us; speedup vs baseline: 5.7909x; 1.2232x over previous
//
#include <hip/hip_runtime.h>

// N=50000, E=800000, CUR=128, HID=96, OUT=128 (derived at runtime)

typedef __attribute__((ext_vector_type(8))) short bf16x8;   // MFMA A/B frag
typedef __attribute__((ext_vector_type(4))) float f32x4;    // MFMA C/D frag

// ---------------------------------------------------------------------------
__device__ __forceinline__ float bf2f(unsigned short u) {
    return __uint_as_float(((unsigned)u) << 16);
}
__device__ __forceinline__ unsigned short f2bf(float f) {
    unsigned u = __float_as_uint(f);
    return (unsigned short)((u + 0x7FFFu + ((u >> 16) & 1u)) >> 16);
}

// ---------------------------------------------------------------------------
// K0: detect int64 vs int32 edge_index. Deterministic.
__global__ void k_flag(const unsigned* __restrict__ ei, int* __restrict__ flag) {
    __shared__ int bad;
    if (threadIdx.x == 0) bad = 0;
    __syncthreads();
    unsigned w = ei[2 * threadIdx.x + 1];
    if (w != 0) atomicAdd(&bad, 1);
    __syncthreads();
    if (threadIdx.x == 0) *flag = (bad == 0) ? 1 : 0;  // 1 => int64
}

__device__ __forceinline__ int edge_src(const int* ei, int e, int E, int flag) {
    return flag ? ei[2 * e] : ei[e];
}
__device__ __forceinline__ int edge_dst(const int* ei, int e, int E, int flag) {
    return flag ? ei[2 * (E + e)] : ei[E + e];
}

// ---------------------------------------------------------------------------
// Weight repack into MFMA-B-fragment-contiguous layout (see R3 notes).
__global__ void k_wprep(const float* __restrict__ Wl, const float* __restrict__ Wr,
                        const float* __restrict__ Wa, const float* __restrict__ Va,
                        const float* __restrict__ preW,
                        unsigned short* __restrict__ Wf_s,
                        unsigned short* __restrict__ Wf_a,
                        unsigned short* __restrict__ Wfp) {
    int tid = blockIdx.x * blockDim.x + threadIdx.x;
    if (tid < 6144) {  // main weights: 2 mats x 6 ksteps x 4 g x 128 j
        int mat = tid / 3072, rem = tid % 3072;
        int kstep = rem / 512, rem2 = rem % 512;
        int g = rem2 / 128, j = rem2 % 128;
        int k0 = kstep * 32 + g * 8;
        const float* Wtop = mat ? Wa : Wl;
        const float* Wbot = mat ? Va : Wr;
        unsigned short* dst = (mat ? Wf_a : Wf_s) + (((size_t)(kstep * 4 + g) * 128 + j) * 8);
#pragma unroll
        for (int kk = 0; kk < 8; kk++) {
            int k = k0 + kk;
            float v = (k < 96) ? Wtop[k * 128 + j] : Wbot[(k - 96) * 128 + j];
            dst[kk] = f2bf(v);
        }
    } else if (tid < 7680) {  // pre weights: 4 ksteps x 4 g x 96 j
        int rem = tid - 6144;
        int kstep = rem / 384, rem2 = rem % 384;
        int g = rem2 / 96, j = rem2 % 96;
        int k0 = kstep * 32 + g * 8;
        unsigned short* dst = Wfp + (((size_t)(kstep * 4 + g) * 96 + j) * 8);
#pragma unroll
        for (int kk = 0; kk < 8; kk++) dst[kk] = f2bf(preW[(k0 + kk) * 96 + j]);
    }
}

// ---------------------------------------------------------------------------
// K1: xh = x @ pre_W + pre_b -> bf16 [N,96], MFMA 16x16x32. 64 nodes/block.
__global__ __launch_bounds__(256) void k_xh(const float* __restrict__ x,
                                            const unsigned short* __restrict__ Wfp,
                                            const float* __restrict__ b,
                                            unsigned short* __restrict__ xhbf, int N) {
    __shared__ unsigned short X[64][136];  // 136 shorts = 17x16B (odd) => 2-way max
    int t = threadIdx.x;
    int nb = blockIdx.x * 64;
    for (int u = t; u < 2048; u += 256) {
        int row = u >> 5, q = u & 31;
        long gn = nb + row;
        float4 v = (gn < N) ? ((const float4*)(x + gn * 128))[q]
                            : make_float4(0.f, 0.f, 0.f, 0.f);
        unsigned short* p = &X[row][q * 4];
        p[0] = f2bf(v.x); p[1] = f2bf(v.y); p[2] = f2bf(v.z); p[3] = f2bf(v.w);
    }
    __syncthreads();
    int lane = t & 63, w = t >> 6;
    int lr = lane & 15, lg = lane >> 4;
    bf16x8 a[4];
#pragma unroll
    for (int ks = 0; ks < 4; ks++)
        a[ks] = *(const bf16x8*)&X[w * 16 + lr][ks * 32 + lg * 8];
    for (int jt = 0; jt < 6; jt++) {
        f32x4 acc = {0.f, 0.f, 0.f, 0.f};
#pragma unroll
        for (int ks = 0; ks < 4; ks++) {
            bf16x8 bf = *(const bf16x8*)(Wfp + (((size_t)(ks * 4 + lg) * 96 + jt * 16 + lr) * 8));
            acc = __builtin_amdgcn_mfma_f32_16x16x32_bf16(a[ks], bf, acc, 0, 0, 0);
        }
        int h = jt * 16 + lr;
        float bb = b[h];
#pragma unroll
        for (int r = 0; r < 4; r++) {
            long n = nb + w * 16 + lg * 4 + r;
            if (n < N) xhbf[n * 96 + h] = f2bf(acc[r] + bb);
        }
    }
}

// ---------------------------------------------------------------------------
// K2: per-edge degree / count
__global__ void k_deg(const int* __restrict__ ei, const float* __restrict__ ew,
                      float* __restrict__ deg, float* __restrict__ cnt, int E,
                      const int* __restrict__ flagp) {
    int e = blockIdx.x * blockDim.x + threadIdx.x;
    if (e >= E) return;
    int flag = *flagp;
    int d = edge_dst(ei, e, E, flag);
    atomicAdd(&deg[d], ew[e]);
    atomicAdd(&cnt[d], 1.0f);
}

// K3: dinv (ARMA) and 1/max(cnt,1) (SAGE)
__global__ void k_dinv(const float* __restrict__ deg, const float* __restrict__ cnt,
                       float* __restrict__ dinv, float* __restrict__ minv, int N) {
    int n = blockIdx.x * blockDim.x + threadIdx.x;
    if (n >= N) return;
    float dg = deg[n];
    dinv[n] = dg > 0.f ? rsqrtf(fmaxf(dg, 1e-30f)) : 0.f;
    minv[n] = 1.f / fmaxf(cnt[n], 1.f);
}

// ---------------------------------------------------------------------------
// Prefix scan of cnt -> offs
__global__ void k_scan_blk(const float* __restrict__ cnt, int* __restrict__ offs,
                           int* __restrict__ bsum, int N) {
    __shared__ int sh[256];
    int t = threadIdx.x;
    int n = blockIdx.x * 256 + t;
    int v = (n < N) ? (int)cnt[n] : 0;
    sh[t] = v;
    __syncthreads();
    for (int off = 1; off < 256; off <<= 1) {
        int add = (t >= off) ? sh[t - off] : 0;
        __syncthreads();
        sh[t] += add;
        __syncthreads();
    }
    if (n < N) offs[n + 1] = sh[t];
    if (t == 255) bsum[blockIdx.x] = sh[255];
    if (blockIdx.x == 0 && t == 0) offs[0] = 0;
}

__global__ void k_scan_top(int* __restrict__ bsum, int nb) {
    __shared__ int sh[256];
    int t = threadIdx.x;
    sh[t] = (t < nb) ? bsum[t] : 0;
    __syncthreads();
    for (int off = 1; off < 256; off <<= 1) {
        int add = (t >= off) ? sh[t - off] : 0;
        __syncthreads();
        sh[t] += add;
        __syncthreads();
    }
    bsum[t] = sh[t];
}

__global__ void k_scan_add(int* __restrict__ offs, const int* __restrict__ bsum, int N) {
    int t = threadIdx.x;
    int n = blockIdx.x * 256 + t;
    if (n < N && blockIdx.x > 0) offs[n + 1] += bsum[blockIdx.x - 1];
}

// ---------------------------------------------------------------------------
// K4: fill CSR: esrc + packed weights ewSA = {ew, dinv[src]*ew}
__global__ void k_fill(const int* __restrict__ ei, const float* __restrict__ ew,
                       const float* __restrict__ dinv, const int* __restrict__ offs,
                       int* __restrict__ cursor, int* __restrict__ esrc,
                       float2* __restrict__ ewSA, int E,
                       const int* __restrict__ flagp) {
    int e = blockIdx.x * blockDim.x + threadIdx.x;
    if (e >= E) return;
    int flag = *flagp;
    int s = edge_src(ei, e, E, flag);
    int d = edge_dst(ei, e, E, flag);
    int pos = atomicAdd(&cursor[d], 1);
    int idx = offs[d] + pos;
    float w = ew[e];
    esrc[idx] = s;
    ewSA[idx] = make_float2(w, dinv[s] * w);
}

// ---------------------------------------------------------------------------
// K5: gather per dst (1 wave/dst). 4-deep unroll for MLP; edge metadata is
// wave-uniform (readfirstlane'd d) -> scalar loads on the SMEM pipe.
__global__ __launch_bounds__(256) void k_gather(
    const int* __restrict__ esrc, const float2* __restrict__ ewSA,
    const unsigned short* __restrict__ xhbf, const int* __restrict__ offs,
    const float* __restrict__ dinv, const float* __restrict__ minv,
    unsigned short* __restrict__ meanbf, unsigned short* __restrict__ propbf, int N) {
    int lane = threadIdx.x & 63;
    int d = __builtin_amdgcn_readfirstlane(blockIdx.x * 4 + (threadIdx.x >> 6));
    if (d >= N) return;
    int beg = offs[d], end = offs[d + 1];
    bool act = lane < 48;
    int col = 2 * lane;
    float s0 = 0.f, s1 = 0.f, a0 = 0.f, a1 = 0.f;
    int e = beg;
    for (; e + 4 <= end; e += 4) {
        int iA = esrc[e], iB = esrc[e + 1], iC = esrc[e + 2], iD = esrc[e + 3];
        float2 wA = ewSA[e], wB = ewSA[e + 1], wC = ewSA[e + 2], wD = ewSA[e + 3];
        unsigned vA = 0, vB = 0, vC = 0, vD = 0;
        if (act) {
            vA = *(const unsigned*)(xhbf + (size_t)iA * 96 + col);
            vB = *(const unsigned*)(xhbf + (size_t)iB * 96 + col);
            vC = *(const unsigned*)(xhbf + (size_t)iC * 96 + col);
            vD = *(const unsigned*)(xhbf + (size_t)iD * 96 + col);
        }
        float xA0 = bf2f((unsigned short)(vA & 0xffff)), xA1 = bf2f((unsigned short)(vA >> 16));
        float xB0 = bf2f((unsigned short)(vB & 0xffff)), xB1 = bf2f((unsigned short)(vB >> 16));
        float xC0 = bf2f((unsigned short)(vC & 0xffff)), xC1 = bf2f((unsigned short)(vC >> 16));
        float xD0 = bf2f((unsigned short)(vD & 0xffff)), xD1 = bf2f((unsigned short)(vD >> 16));
        s0 += wA.x * xA0 + wB.x * xB0 + wC.x * xC0 + wD.x * xD0;
        s1 += wA.x * xA1 + wB.x * xB1 + wC.x * xC1 + wD.x * xD1;
        a0 += wA.y * xA0 + wB.y * xB0 + wC.y * xC0 + wD.y * xD0;
        a1 += wA.y * xA1 + wB.y * xB1 + wC.y * xC1 + wD.y * xD1;
    }
    for (; e < end; e++) {
        int s = esrc[e];
        float2 w2 = ewSA[e];
        if (act) {
            unsigned v = *(const unsigned*)(xhbf + (size_t)s * 96 + col);
            float x0 = bf2f((unsigned short)(v & 0xffff));
            float x1 = bf2f((unsigned short)(v >> 16));
            s0 += w2.x * x0; s1 += w2.x * x1;
            a0 += w2.y * x0; a1 += w2.y * x1;
        }
    }
    if (act) {
        float mi = minv[d], di = dinv[d];
        unsigned mo = (unsigned)f2bf(s0 * mi) | ((unsigned)f2bf(s1 * mi) << 16);
        unsigned po = (unsigned)f2bf(a0 * di) | ((unsigned)f2bf(a1 * di) << 16);
        *(unsigned*)(meanbf + (size_t)d * 96 + col) = mo;
        *(unsigned*)(propbf + (size_t)d * 96 + col) = po;
    }
}

// ---------------------------------------------------------------------------
// K6: epilogue via two K=192 MFMA GEMMs (see R3). 64 nodes/block.
__global__ __launch_bounds__(256) void k_out(
    const unsigned short* __restrict__ meanbf, const unsigned short* __restrict__ propbf,
    const unsigned short* __restrict__ xhbf, const unsigned short* __restrict__ Wf_s,
    const unsigned short* __restrict__ Wf_a, const float* __restrict__ bl,
    const float* __restrict__ ba, float* __restrict__ out, int N) {
    __shared__ unsigned short A[3][64][104];  // 104 shorts = 13x16B (odd) => 2-way max
    int t = threadIdx.x;
    int nb = blockIdx.x * 64;
    for (int u = t; u < 2304; u += 256) {
        int arr = u / 768, rem = u - arr * 768;
        int row = rem / 12, c = rem - row * 12;
        long gn = nb + row;
        const unsigned short* src = (arr == 0) ? meanbf : (arr == 1) ? propbf : xhbf;
        float4 v = (gn < N) ? *(const float4*)(src + gn * 96 + c * 8)
                            : make_float4(0.f, 0.f, 0.f, 0.f);
        *(float4*)&A[arr][row][c * 8] = v;
    }
    __syncthreads();
    int lane = t & 63, w = t >> 6;
    int lr = lane & 15, lg = lane >> 4;
    bf16x8 am[3], ap[3], ax[3];
#pragma unroll
    for (int ks = 0; ks < 3; ks++) {
        int row = w * 16 + lr, kc = ks * 32 + lg * 8;
        am[ks] = *(const bf16x8*)&A[0][row][kc];
        ap[ks] = *(const bf16x8*)&A[1][row][kc];
        ax[ks] = *(const bf16x8*)&A[2][row][kc];
    }
    for (int jt = 0; jt < 8; jt++) {
        f32x4 accS = {0.f, 0.f, 0.f, 0.f};
        f32x4 accA = {0.f, 0.f, 0.f, 0.f};
#pragma unroll
        for (int ks = 0; ks < 3; ks++) {
            size_t boffS = ((size_t)(ks * 4 + lg) * 128 + jt * 16 + lr) * 8;
            size_t boffS2 = ((size_t)((ks + 3) * 4 + lg) * 128 + jt * 16 + lr) * 8;
            bf16x8 b0 = *(const bf16x8*)(Wf_s + boffS);
            bf16x8 b1 = *(const bf16x8*)(Wf_s + boffS2);
            bf16x8 b2 = *(const bf16x8*)(Wf_a + boffS);
            bf16x8 b3 = *(const bf16x8*)(Wf_a + boffS2);
            accS = __builtin_amdgcn_mfma_f32_16x16x32_bf16(am[ks], b0, accS, 0, 0, 0);
            accS = __builtin_amdgcn_mfma_f32_16x16x32_bf16(ax[ks], b1, accS, 0, 0, 0);
            accA = __builtin_amdgcn_mfma_f32_16x16x32_bf16(ap[ks], b2, accA, 0, 0, 0);
            accA = __builtin_amdgcn_mfma_f32_16x16x32_bf16(ax[ks], b3, accA, 0, 0, 0);
        }
        int j = jt * 16 + lr;
        float blj = bl[j], baj = ba[j];
#pragma unroll
        for (int r = 0; r < 4; r++) {
            long n = nb + w * 16 + lg * 4 + r;
            if (n < N) {
                float os = accS[r] + blj;
                float oa = fmaxf(accA[r] + baj, 0.f);
                float o1 = os > 0.f ? os : 0.01f * os;
                float o2 = oa > 0.f ? oa : 0.01f * oa;
                out[n * 128 + j] = fmaxf(o1 + o2, 0.f);
            }
        }
    }
}

// ---------------------------------------------------------------------------
extern "C" void kernel_launch(void* const* d_in, const int* in_sizes, int n_in,
                              void* d_out, int out_size, void* d_ws, size_t ws_size,
                              hipStream_t stream) {
    const float* x    = (const float*)d_in[1];
    const int*   ei   = (const int*)d_in[2];
    const float* ew   = (const float*)d_in[3];
    const float* preW = (const float*)d_in[4];
    const float* preb = (const float*)d_in[5];
    const float* Wl   = (const float*)d_in[6];
    const float* bl   = (const float*)d_in[7];
    const float* Wr   = (const float*)d_in[8];
    const float* Wa   = (const float*)d_in[9];
    const float* Va   = (const float*)d_in[10];
    const float* ba   = (const float*)d_in[11];

    const int N = in_sizes[1] / 128;
    const int E = in_sizes[3];
    const int NB = (N + 255) / 256;

    // ws layout
    char* w = (char*)d_ws;
    unsigned short* xhbf   = (unsigned short*)w; w += (size_t)N * 96 * 2;
    unsigned short* meanbf = (unsigned short*)w; w += (size_t)N * 96 * 2;
    unsigned short* propbf = (unsigned short*)w; w += (size_t)N * 96 * 2;
    unsigned short* Wf_s   = (unsigned short*)w; w += (size_t)6 * 4 * 128 * 8 * 2;
    unsigned short* Wf_a   = (unsigned short*)w; w += (size_t)6 * 4 * 128 * 8 * 2;
    unsigned short* Wfp    = (unsigned short*)w; w += (size_t)4 * 4 * 96 * 8 * 2;
    int*    esrc = (int*)w;    w += (size_t)E * 4;
    float2* ewSA = (float2*)w; w += (size_t)E * 8;
    float* deg  = (float*)w; w += (size_t)N * 4;
    float* cnt  = (float*)w; w += (size_t)N * 4;
    int*   cursor = (int*)w; w += (size_t)N * 4;
    float* dinv = (float*)w; w += (size_t)N * 4;
    float* minv = (float*)w; w += (size_t)N * 4;
    int*   offs = (int*)w;   w += (size_t)(N + 1) * 4;
    int*   bsum = (int*)w;   w += 256 * 4;
    int*   flag = (int*)w;

    // zero deg, cnt, cursor (contiguous)
    hipMemsetAsync(deg, 0, (size_t)N * 3 * 4, stream);

    k_flag<<<1, 1024, 0, stream>>>((const unsigned*)ei, flag);
    k_wprep<<<30, 256, 0, stream>>>(Wl, Wr, Wa, Va, preW, Wf_s, Wf_a, Wfp);
    k_xh<<<(N + 63) / 64, 256, 0, stream>>>(x, Wfp, preb, xhbf, N);
    k_deg<<<(E + 255) / 256, 256, 0, stream>>>(ei, ew, deg, cnt, E, flag);
    k_dinv<<<NB, 256, 0, stream>>>(deg, cnt, dinv, minv, N);
    k_scan_blk<<<NB, 256, 0, stream>>>(cnt, offs, bsum, N);
    k_scan_top<<<1, 256, 0, stream>>>(bsum, NB);
    k_scan_add<<<NB, 256, 0, stream>>>(offs, bsum, N);
    k_fill<<<(E + 255) / 256, 256, 0, stream>>>(ei, ew, dinv, offs, cursor, esrc,
                                                ewSA, E, flag);
    k_gather<<<(N + 3) / 4, 256, 0, stream>>>(esrc, ewSA, xhbf, offs, dinv,
                                              minv, meanbf, propbf, N);
    // output 0: his = x
    hipMemcpyAsync(d_out, (void*)x, (size_t)N * 128 * sizeof(float),
                   hipMemcpyDeviceToDevice, stream);
    // output 1: o3
    k_out<<<(N + 63) / 64, 256, 0, stream>>>(meanbf, propbf, xhbf, Wf_s, Wf_a,
                                             bl, ba, (float*)d_out + (size_t)N * 128, N);
}

// Round 6
// 165.796 us; speedup vs baseline: 8.0702x; 1.3936x over previous
//
#include <hip/hip_runtime.h>

// N=50000, E=800000, CUR=128, HID=96, OUT=128 (derived at runtime)

typedef __attribute__((ext_vector_type(8))) short bf16x8;   // MFMA A/B frag
typedef __attribute__((ext_vector_type(4))) float f32x4;    // MFMA C/D frag

// ---------------------------------------------------------------------------
__device__ __forceinline__ float bf2f(unsigned short u) {
    return __uint_as_float(((unsigned)u) << 16);
}
__device__ __forceinline__ unsigned short f2bf(float f) {
    unsigned u = __float_as_uint(f);
    return (unsigned short)((u + 0x7FFFu + ((u >> 16) & 1u)) >> 16);
}

// ---------------------------------------------------------------------------
// K0: detect int64 vs int32 edge_index. Deterministic.
__global__ void k_flag(const unsigned* __restrict__ ei, int* __restrict__ flag) {
    __shared__ int bad;
    if (threadIdx.x == 0) bad = 0;
    __syncthreads();
    unsigned w = ei[2 * threadIdx.x + 1];
    if (w != 0) atomicAdd(&bad, 1);
    __syncthreads();
    if (threadIdx.x == 0) *flag = (bad == 0) ? 1 : 0;  // 1 => int64
}

__device__ __forceinline__ int edge_src(const int* ei, int e, int E, int flag) {
    return flag ? ei[2 * e] : ei[e];
}
__device__ __forceinline__ int edge_dst(const int* ei, int e, int E, int flag) {
    return flag ? ei[2 * (E + e)] : ei[E + e];
}

// ---------------------------------------------------------------------------
// Weight repack into MFMA-B-fragment-contiguous layout (see R3 notes).
__global__ void k_wprep(const float* __restrict__ Wl, const float* __restrict__ Wr,
                        const float* __restrict__ Wa, const float* __restrict__ Va,
                        const float* __restrict__ preW,
                        unsigned short* __restrict__ Wf_s,
                        unsigned short* __restrict__ Wf_a,
                        unsigned short* __restrict__ Wfp) {
    int tid = blockIdx.x * blockDim.x + threadIdx.x;
    if (tid < 6144) {  // main weights: 2 mats x 6 ksteps x 4 g x 128 j
        int mat = tid / 3072, rem = tid % 3072;
        int kstep = rem / 512, rem2 = rem % 512;
        int g = rem2 / 128, j = rem2 % 128;
        int k0 = kstep * 32 + g * 8;
        const float* Wtop = mat ? Wa : Wl;
        const float* Wbot = mat ? Va : Wr;
        unsigned short* dst = (mat ? Wf_a : Wf_s) + (((size_t)(kstep * 4 + g) * 128 + j) * 8);
#pragma unroll
        for (int kk = 0; kk < 8; kk++) {
            int k = k0 + kk;
            float v = (k < 96) ? Wtop[k * 128 + j] : Wbot[(k - 96) * 128 + j];
            dst[kk] = f2bf(v);
        }
    } else if (tid < 7680) {  // pre weights: 4 ksteps x 4 g x 96 j
        int rem = tid - 6144;
        int kstep = rem / 384, rem2 = rem % 384;
        int g = rem2 / 96, j = rem2 % 96;
        int k0 = kstep * 32 + g * 8;
        unsigned short* dst = Wfp + (((size_t)(kstep * 4 + g) * 96 + j) * 8);
#pragma unroll
        for (int kk = 0; kk < 8; kk++) dst[kk] = f2bf(preW[(k0 + kk) * 96 + j]);
    }
}

// ---------------------------------------------------------------------------
// K1: xh = x @ pre_W + pre_b -> bf16 [N,96], MFMA 16x16x32. 64 nodes/block.
// Also emits his = x to out0 (fuses away the D2D memcpy; x is read anyway).
__global__ __launch_bounds__(256) void k_xh(const float* __restrict__ x,
                                            const unsigned short* __restrict__ Wfp,
                                            const float* __restrict__ b,
                                            unsigned short* __restrict__ xhbf,
                                            float* __restrict__ out0, int N) {
    __shared__ unsigned short X[64][136];  // 136 shorts = 17x16B (odd) => 2-way max
    int t = threadIdx.x;
    int nb = blockIdx.x * 64;
    for (int u = t; u < 2048; u += 256) {
        int row = u >> 5, q = u & 31;
        long gn = nb + row;
        float4 v = make_float4(0.f, 0.f, 0.f, 0.f);
        if (gn < N) {
            v = ((const float4*)(x + gn * 128))[q];
            ((float4*)(out0 + gn * 128))[q] = v;  // his = x
        }
        unsigned short* p = &X[row][q * 4];
        p[0] = f2bf(v.x); p[1] = f2bf(v.y); p[2] = f2bf(v.z); p[3] = f2bf(v.w);
    }
    __syncthreads();
    int lane = t & 63, w = t >> 6;
    int lr = lane & 15, lg = lane >> 4;
    bf16x8 a[4];
#pragma unroll
    for (int ks = 0; ks < 4; ks++)
        a[ks] = *(const bf16x8*)&X[w * 16 + lr][ks * 32 + lg * 8];
    for (int jt = 0; jt < 6; jt++) {
        f32x4 acc = {0.f, 0.f, 0.f, 0.f};
#pragma unroll
        for (int ks = 0; ks < 4; ks++) {
            bf16x8 bf = *(const bf16x8*)(Wfp + (((size_t)(ks * 4 + lg) * 96 + jt * 16 + lr) * 8));
            acc = __builtin_amdgcn_mfma_f32_16x16x32_bf16(a[ks], bf, acc, 0, 0, 0);
        }
        int h = jt * 16 + lr;
        float bb = b[h];
#pragma unroll
        for (int r = 0; r < 4; r++) {
            long n = nb + w * 16 + lg * 4 + r;
            if (n < N) xhbf[n * 96 + h] = f2bf(acc[r] + bb);
        }
    }
}

// ---------------------------------------------------------------------------
// K2: rank+count in ONE int atomic per edge. pos[e] = rank of e within dst.
__global__ void k_count(const int* __restrict__ ei, int* __restrict__ cnt_i,
                        int* __restrict__ pos, int E, const int* __restrict__ flagp) {
    int e = blockIdx.x * blockDim.x + threadIdx.x;
    if (e >= E) return;
    int flag = *flagp;
    int d = edge_dst(ei, e, E, flag);
    pos[e] = atomicAdd(&cnt_i[d], 1);
}

// ---------------------------------------------------------------------------
// Prefix scan of cnt_i -> offs
__global__ void k_scan_blk(const int* __restrict__ cnt, int* __restrict__ offs,
                           int* __restrict__ bsum, int N) {
    __shared__ int sh[256];
    int t = threadIdx.x;
    int n = blockIdx.x * 256 + t;
    int v = (n < N) ? cnt[n] : 0;
    sh[t] = v;
    __syncthreads();
    for (int off = 1; off < 256; off <<= 1) {
        int add = (t >= off) ? sh[t - off] : 0;
        __syncthreads();
        sh[t] += add;
        __syncthreads();
    }
    if (n < N) offs[n + 1] = sh[t];
    if (t == 255) bsum[blockIdx.x] = sh[255];
    if (blockIdx.x == 0 && t == 0) offs[0] = 0;
}

__global__ void k_scan_top(int* __restrict__ bsum, int nb) {
    __shared__ int sh[256];
    int t = threadIdx.x;
    sh[t] = (t < nb) ? bsum[t] : 0;
    __syncthreads();
    for (int off = 1; off < 256; off <<= 1) {
        int add = (t >= off) ? sh[t - off] : 0;
        __syncthreads();
        sh[t] += add;
        __syncthreads();
    }
    bsum[t] = sh[t];
}

__global__ void k_scan_add(int* __restrict__ offs, const int* __restrict__ bsum, int N) {
    int t = threadIdx.x;
    int n = blockIdx.x * 256 + t;
    if (n < N && blockIdx.x > 0) offs[n + 1] += bsum[blockIdx.x - 1];
}

// ---------------------------------------------------------------------------
// K4: fill CSR with NO atomics: idx = offs[d] + pos[e].
__global__ void k_fill(const int* __restrict__ ei, const float* __restrict__ ew,
                       const int* __restrict__ offs, const int* __restrict__ pos,
                       int* __restrict__ esrc, float* __restrict__ eww, int E,
                       const int* __restrict__ flagp) {
    int e = blockIdx.x * blockDim.x + threadIdx.x;
    if (e >= E) return;
    int flag = *flagp;
    int s = edge_src(ei, e, E, flag);
    int d = edge_dst(ei, e, E, flag);
    int idx = offs[d] + pos[e];
    esrc[idx] = s;
    eww[idx] = ew[e];
}

// ---------------------------------------------------------------------------
// K4b: per-dst degree from CSR segment (sequential, no atomics) -> dinv, minv.
__global__ void k_degcsr(const float* __restrict__ eww, const int* __restrict__ offs,
                         float* __restrict__ dinv, float* __restrict__ minv, int N) {
    int n = blockIdx.x * blockDim.x + threadIdx.x;
    if (n >= N) return;
    int beg = offs[n], end = offs[n + 1];
    float dg = 0.f;
    for (int e = beg; e < end; e++) dg += eww[e];
    dinv[n] = dg > 0.f ? rsqrtf(fmaxf(dg, 1e-30f)) : 0.f;
    minv[n] = 1.f / fmaxf((float)(end - beg), 1.f);
}

// ---------------------------------------------------------------------------
// K5: gather per dst (1 wave/dst), 4-deep unroll; wA = dinv[src]*w inline
// (scalar loads: e/beg/end wave-uniform -> esrc/eww/dinv[src] on SMEM pipe).
__global__ __launch_bounds__(256) void k_gather(
    const int* __restrict__ esrc, const float* __restrict__ eww,
    const unsigned short* __restrict__ xhbf, const int* __restrict__ offs,
    const float* __restrict__ dinv, const float* __restrict__ minv,
    unsigned short* __restrict__ meanbf, unsigned short* __restrict__ propbf, int N) {
    int lane = threadIdx.x & 63;
    int d = __builtin_amdgcn_readfirstlane(blockIdx.x * 4 + (threadIdx.x >> 6));
    if (d >= N) return;
    int beg = offs[d], end = offs[d + 1];
    bool act = lane < 48;
    int col = 2 * lane;
    float s0 = 0.f, s1 = 0.f, a0 = 0.f, a1 = 0.f;
    int e = beg;
    for (; e + 4 <= end; e += 4) {
        int iA = esrc[e], iB = esrc[e + 1], iC = esrc[e + 2], iD = esrc[e + 3];
        float wA = eww[e], wB = eww[e + 1], wC = eww[e + 2], wD = eww[e + 3];
        float dA = dinv[iA], dB = dinv[iB], dC = dinv[iC], dD = dinv[iD];
        unsigned vA = 0, vB = 0, vC = 0, vD = 0;
        if (act) {
            vA = *(const unsigned*)(xhbf + (size_t)iA * 96 + col);
            vB = *(const unsigned*)(xhbf + (size_t)iB * 96 + col);
            vC = *(const unsigned*)(xhbf + (size_t)iC * 96 + col);
            vD = *(const unsigned*)(xhbf + (size_t)iD * 96 + col);
        }
        float xA0 = bf2f((unsigned short)(vA & 0xffff)), xA1 = bf2f((unsigned short)(vA >> 16));
        float xB0 = bf2f((unsigned short)(vB & 0xffff)), xB1 = bf2f((unsigned short)(vB >> 16));
        float xC0 = bf2f((unsigned short)(vC & 0xffff)), xC1 = bf2f((unsigned short)(vC >> 16));
        float xD0 = bf2f((unsigned short)(vD & 0xffff)), xD1 = bf2f((unsigned short)(vD >> 16));
        s0 += wA * xA0 + wB * xB0 + wC * xC0 + wD * xD0;
        s1 += wA * xA1 + wB * xB1 + wC * xC1 + wD * xD1;
        a0 += dA * wA * xA0 + dB * wB * xB0 + dC * wC * xC0 + dD * wD * xD0;
        a1 += dA * wA * xA1 + dB * wB * xB1 + dC * wC * xC1 + dD * wD * xD1;
    }
    for (; e < end; e++) {
        int s = esrc[e];
        float w2 = eww[e];
        float ds = dinv[s];
        if (act) {
            unsigned v = *(const unsigned*)(xhbf + (size_t)s * 96 + col);
            float x0 = bf2f((unsigned short)(v & 0xffff));
            float x1 = bf2f((unsigned short)(v >> 16));
            s0 += w2 * x0; s1 += w2 * x1;
            a0 += ds * w2 * x0; a1 += ds * w2 * x1;
        }
    }
    if (act) {
        float mi = minv[d], di = dinv[d];
        unsigned mo = (unsigned)f2bf(s0 * mi) | ((unsigned)f2bf(s1 * mi) << 16);
        unsigned po = (unsigned)f2bf(a0 * di) | ((unsigned)f2bf(a1 * di) << 16);
        *(unsigned*)(meanbf + (size_t)d * 96 + col) = mo;
        *(unsigned*)(propbf + (size_t)d * 96 + col) = po;
    }
}

// ---------------------------------------------------------------------------
// K6: epilogue via two K=192 MFMA GEMMs (see R3). 64 nodes/block.
__global__ __launch_bounds__(256) void k_out(
    const unsigned short* __restrict__ meanbf, const unsigned short* __restrict__ propbf,
    const unsigned short* __restrict__ xhbf, const unsigned short* __restrict__ Wf_s,
    const unsigned short* __restrict__ Wf_a, const float* __restrict__ bl,
    const float* __restrict__ ba, float* __restrict__ out, int N) {
    __shared__ unsigned short A[3][64][104];  // 104 shorts = 13x16B (odd) => 2-way max
    int t = threadIdx.x;
    int nb = blockIdx.x * 64;
    for (int u = t; u < 2304; u += 256) {
        int arr = u / 768, rem = u - arr * 768;
        int row = rem / 12, c = rem - row * 12;
        long gn = nb + row;
        const unsigned short* src = (arr == 0) ? meanbf : (arr == 1) ? propbf : xhbf;
        float4 v = (gn < N) ? *(const float4*)(src + gn * 96 + c * 8)
                            : make_float4(0.f, 0.f, 0.f, 0.f);
        *(float4*)&A[arr][row][c * 8] = v;
    }
    __syncthreads();
    int lane = t & 63, w = t >> 6;
    int lr = lane & 15, lg = lane >> 4;
    bf16x8 am[3], ap[3], ax[3];
#pragma unroll
    for (int ks = 0; ks < 3; ks++) {
        int row = w * 16 + lr, kc = ks * 32 + lg * 8;
        am[ks] = *(const bf16x8*)&A[0][row][kc];
        ap[ks] = *(const bf16x8*)&A[1][row][kc];
        ax[ks] = *(const bf16x8*)&A[2][row][kc];
    }
    for (int jt = 0; jt < 8; jt++) {
        f32x4 accS = {0.f, 0.f, 0.f, 0.f};
        f32x4 accA = {0.f, 0.f, 0.f, 0.f};
#pragma unroll
        for (int ks = 0; ks < 3; ks++) {
            size_t boffS = ((size_t)(ks * 4 + lg) * 128 + jt * 16 + lr) * 8;
            size_t boffS2 = ((size_t)((ks + 3) * 4 + lg) * 128 + jt * 16 + lr) * 8;
            bf16x8 b0 = *(const bf16x8*)(Wf_s + boffS);
            bf16x8 b1 = *(const bf16x8*)(Wf_s + boffS2);
            bf16x8 b2 = *(const bf16x8*)(Wf_a + boffS);
            bf16x8 b3 = *(const bf16x8*)(Wf_a + boffS2);
            accS = __builtin_amdgcn_mfma_f32_16x16x32_bf16(am[ks], b0, accS, 0, 0, 0);
            accS = __builtin_amdgcn_mfma_f32_16x16x32_bf16(ax[ks], b1, accS, 0, 0, 0);
            accA = __builtin_amdgcn_mfma_f32_16x16x32_bf16(ap[ks], b2, accA, 0, 0, 0);
            accA = __builtin_amdgcn_mfma_f32_16x16x32_bf16(ax[ks], b3, accA, 0, 0, 0);
        }
        int j = jt * 16 + lr;
        float blj = bl[j], baj = ba[j];
#pragma unroll
        for (int r = 0; r < 4; r++) {
            long n = nb + w * 16 + lg * 4 + r;
            if (n < N) {
                float os = accS[r] + blj;
                float oa = fmaxf(accA[r] + baj, 0.f);
                float o1 = os > 0.f ? os : 0.01f * os;
                float o2 = oa > 0.f ? oa : 0.01f * oa;
                out[n * 128 + j] = fmaxf(o1 + o2, 0.f);
            }
        }
    }
}

// ---------------------------------------------------------------------------
extern "C" void kernel_launch(void* const* d_in, const int* in_sizes, int n_in,
                              void* d_out, int out_size, void* d_ws, size_t ws_size,
                              hipStream_t stream) {
    const float* x    = (const float*)d_in[1];
    const int*   ei   = (const int*)d_in[2];
    const float* ew   = (const float*)d_in[3];
    const float* preW = (const float*)d_in[4];
    const float* preb = (const float*)d_in[5];
    const float* Wl   = (const float*)d_in[6];
    const float* bl   = (const float*)d_in[7];
    const float* Wr   = (const float*)d_in[8];
    const float* Wa   = (const float*)d_in[9];
    const float* Va   = (const float*)d_in[10];
    const float* ba   = (const float*)d_in[11];

    const int N = in_sizes[1] / 128;
    const int E = in_sizes[3];
    const int NB = (N + 255) / 256;

    // ws layout
    char* w = (char*)d_ws;
    unsigned short* xhbf   = (unsigned short*)w; w += (size_t)N * 96 * 2;
    unsigned short* meanbf = (unsigned short*)w; w += (size_t)N * 96 * 2;
    unsigned short* propbf = (unsigned short*)w; w += (size_t)N * 96 * 2;
    unsigned short* Wf_s   = (unsigned short*)w; w += (size_t)6 * 4 * 128 * 8 * 2;
    unsigned short* Wf_a   = (unsigned short*)w; w += (size_t)6 * 4 * 128 * 8 * 2;
    unsigned short* Wfp    = (unsigned short*)w; w += (size_t)4 * 4 * 96 * 8 * 2;
    int*   esrc = (int*)w;   w += (size_t)E * 4;
    float* eww  = (float*)w; w += (size_t)E * 4;
    int*   pos  = (int*)w;   w += (size_t)E * 4;
    int*   cnt_i = (int*)w;  w += (size_t)N * 4;
    float* dinv = (float*)w; w += (size_t)N * 4;
    float* minv = (float*)w; w += (size_t)N * 4;
    int*   offs = (int*)w;   w += (size_t)(N + 1) * 4;
    int*   bsum = (int*)w;   w += 256 * 4;
    int*   flag = (int*)w;

    // zero cnt_i
    hipMemsetAsync(cnt_i, 0, (size_t)N * 4, stream);

    k_flag<<<1, 1024, 0, stream>>>((const unsigned*)ei, flag);
    k_wprep<<<30, 256, 0, stream>>>(Wl, Wr, Wa, Va, preW, Wf_s, Wf_a, Wfp);
    k_xh<<<(N + 63) / 64, 256, 0, stream>>>(x, Wfp, preb, xhbf, (float*)d_out, N);
    k_count<<<(E + 255) / 256, 256, 0, stream>>>(ei, cnt_i, pos, E, flag);
    k_scan_blk<<<NB, 256, 0, stream>>>(cnt_i, offs, bsum, N);
    k_scan_top<<<1, 256, 0, stream>>>(bsum, NB);
    k_scan_add<<<NB, 256, 0, stream>>>(offs, bsum, N);
    k_fill<<<(E + 255) / 256, 256, 0, stream>>>(ei, ew, offs, pos, esrc, eww, E, flag);
    k_degcsr<<<NB, 256, 0, stream>>>(eww, offs, dinv, minv, N);
    k_gather<<<(N + 3) / 4, 256, 0, stream>>>(esrc, eww, xhbf, offs, dinv,
                                              minv, meanbf, propbf, N);
    k_out<<<(N + 63) / 64, 256, 0, stream>>>(meanbf, propbf, xhbf, Wf_s, Wf_a,
                                             bl, ba, (float*)d_out + (size_t)N * 128, N);
}

// Round 7
// 161.237 us; speedup vs baseline: 8.2984x; 1.0283x over previous
//
#include <hip/hip_runtime.h>

// N=50000, E=800000, CUR=128, HID=96, OUT=128 (derived at runtime)

typedef __attribute__((ext_vector_type(8))) short bf16x8;   // MFMA A/B frag
typedef __attribute__((ext_vector_type(4))) float f32x4;    // MFMA C/D frag

// ---------------------------------------------------------------------------
__device__ __forceinline__ float bf2f(unsigned short u) {
    return __uint_as_float(((unsigned)u) << 16);
}
__device__ __forceinline__ unsigned short f2bf(float f) {
    unsigned u = __float_as_uint(f);
    return (unsigned short)((u + 0x7FFFu + ((u >> 16) & 1u)) >> 16);
}

// ---------------------------------------------------------------------------
// K0: detect int64 vs int32 edge_index. Deterministic.
__global__ void k_flag(const unsigned* __restrict__ ei, int* __restrict__ flag) {
    __shared__ int bad;
    if (threadIdx.x == 0) bad = 0;
    __syncthreads();
    unsigned w = ei[2 * threadIdx.x + 1];
    if (w != 0) atomicAdd(&bad, 1);
    __syncthreads();
    if (threadIdx.x == 0) *flag = (bad == 0) ? 1 : 0;  // 1 => int64
}

__device__ __forceinline__ int edge_src(const int* ei, int e, int E, int flag) {
    return flag ? ei[2 * e] : ei[e];
}
__device__ __forceinline__ int edge_dst(const int* ei, int e, int E, int flag) {
    return flag ? ei[2 * (E + e)] : ei[E + e];
}

// ---------------------------------------------------------------------------
// Weight repack into MFMA-B-fragment-contiguous layout (see R3 notes).
// Also zeroes cnt_i with spare threads (kills the 40us rocclr fillBuffer dispatch;
// stream order guarantees completion before k_count's atomics).
__global__ void k_wprep(const float* __restrict__ Wl, const float* __restrict__ Wr,
                        const float* __restrict__ Wa, const float* __restrict__ Va,
                        const float* __restrict__ preW,
                        unsigned short* __restrict__ Wf_s,
                        unsigned short* __restrict__ Wf_a,
                        unsigned short* __restrict__ Wfp,
                        int4* __restrict__ cnt4, int nz4) {
    int tid = blockIdx.x * blockDim.x + threadIdx.x;
    if (tid < 6144) {  // main weights: 2 mats x 6 ksteps x 4 g x 128 j
        int mat = tid / 3072, rem = tid % 3072;
        int kstep = rem / 512, rem2 = rem % 512;
        int g = rem2 / 128, j = rem2 % 128;
        int k0 = kstep * 32 + g * 8;
        const float* Wtop = mat ? Wa : Wl;
        const float* Wbot = mat ? Va : Wr;
        unsigned short* dst = (mat ? Wf_a : Wf_s) + (((size_t)(kstep * 4 + g) * 128 + j) * 8);
#pragma unroll
        for (int kk = 0; kk < 8; kk++) {
            int k = k0 + kk;
            float v = (k < 96) ? Wtop[k * 128 + j] : Wbot[(k - 96) * 128 + j];
            dst[kk] = f2bf(v);
        }
    } else if (tid < 7680) {  // pre weights: 4 ksteps x 4 g x 96 j
        int rem = tid - 6144;
        int kstep = rem / 384, rem2 = rem % 384;
        int g = rem2 / 96, j = rem2 % 96;
        int k0 = kstep * 32 + g * 8;
        unsigned short* dst = Wfp + (((size_t)(kstep * 4 + g) * 96 + j) * 8);
#pragma unroll
        for (int kk = 0; kk < 8; kk++) dst[kk] = f2bf(preW[(k0 + kk) * 96 + j]);
    } else if (tid >= 8192 && tid < 8192 + nz4) {  // zero cnt_i (int4 stores)
        cnt4[tid - 8192] = make_int4(0, 0, 0, 0);
    }
}

// ---------------------------------------------------------------------------
// K1: xh = x @ pre_W + pre_b -> bf16 [N,96], MFMA 16x16x32. 64 nodes/block.
// Also emits his = x to out0 (fuses away the D2D memcpy; x is read anyway).
__global__ __launch_bounds__(256) void k_xh(const float* __restrict__ x,
                                            const unsigned short* __restrict__ Wfp,
                                            const float* __restrict__ b,
                                            unsigned short* __restrict__ xhbf,
                                            float* __restrict__ out0, int N) {
    __shared__ unsigned short X[64][136];  // 136 shorts = 17x16B (odd) => 2-way max
    int t = threadIdx.x;
    int nb = blockIdx.x * 64;
    for (int u = t; u < 2048; u += 256) {
        int row = u >> 5, q = u & 31;
        long gn = nb + row;
        float4 v = make_float4(0.f, 0.f, 0.f, 0.f);
        if (gn < N) {
            v = ((const float4*)(x + gn * 128))[q];
            ((float4*)(out0 + gn * 128))[q] = v;  // his = x
        }
        unsigned short* p = &X[row][q * 4];
        p[0] = f2bf(v.x); p[1] = f2bf(v.y); p[2] = f2bf(v.z); p[3] = f2bf(v.w);
    }
    __syncthreads();
    int lane = t & 63, w = t >> 6;
    int lr = lane & 15, lg = lane >> 4;
    bf16x8 a[4];
#pragma unroll
    for (int ks = 0; ks < 4; ks++)
        a[ks] = *(const bf16x8*)&X[w * 16 + lr][ks * 32 + lg * 8];
    for (int jt = 0; jt < 6; jt++) {
        f32x4 acc = {0.f, 0.f, 0.f, 0.f};
#pragma unroll
        for (int ks = 0; ks < 4; ks++) {
            bf16x8 bf = *(const bf16x8*)(Wfp + (((size_t)(ks * 4 + lg) * 96 + jt * 16 + lr) * 8));
            acc = __builtin_amdgcn_mfma_f32_16x16x32_bf16(a[ks], bf, acc, 0, 0, 0);
        }
        int h = jt * 16 + lr;
        float bb = b[h];
#pragma unroll
        for (int r = 0; r < 4; r++) {
            long n = nb + w * 16 + lg * 4 + r;
            if (n < N) xhbf[n * 96 + h] = f2bf(acc[r] + bb);
        }
    }
}

// ---------------------------------------------------------------------------
// K2: rank+count in ONE int atomic per edge. pos[e] = rank of e within dst.
__global__ void k_count(const int* __restrict__ ei, int* __restrict__ cnt_i,
                        int* __restrict__ pos, int E, const int* __restrict__ flagp) {
    int e = blockIdx.x * blockDim.x + threadIdx.x;
    if (e >= E) return;
    int flag = *flagp;
    int d = edge_dst(ei, e, E, flag);
    pos[e] = atomicAdd(&cnt_i[d], 1);
}

// ---------------------------------------------------------------------------
// Prefix scan of cnt_i -> offs
__global__ void k_scan_blk(const int* __restrict__ cnt, int* __restrict__ offs,
                           int* __restrict__ bsum, int N) {
    __shared__ int sh[256];
    int t = threadIdx.x;
    int n = blockIdx.x * 256 + t;
    int v = (n < N) ? cnt[n] : 0;
    sh[t] = v;
    __syncthreads();
    for (int off = 1; off < 256; off <<= 1) {
        int add = (t >= off) ? sh[t - off] : 0;
        __syncthreads();
        sh[t] += add;
        __syncthreads();
    }
    if (n < N) offs[n + 1] = sh[t];
    if (t == 255) bsum[blockIdx.x] = sh[255];
    if (blockIdx.x == 0 && t == 0) offs[0] = 0;
}

__global__ void k_scan_top(int* __restrict__ bsum, int nb) {
    __shared__ int sh[256];
    int t = threadIdx.x;
    sh[t] = (t < nb) ? bsum[t] : 0;
    __syncthreads();
    for (int off = 1; off < 256; off <<= 1) {
        int add = (t >= off) ? sh[t - off] : 0;
        __syncthreads();
        sh[t] += add;
        __syncthreads();
    }
    bsum[t] = sh[t];
}

__global__ void k_scan_add(int* __restrict__ offs, const int* __restrict__ bsum, int N) {
    int t = threadIdx.x;
    int n = blockIdx.x * 256 + t;
    if (n < N && blockIdx.x > 0) offs[n + 1] += bsum[blockIdx.x - 1];
}

// ---------------------------------------------------------------------------
// K4: fill CSR with NO atomics: idx = offs[d] + pos[e].
__global__ void k_fill(const int* __restrict__ ei, const float* __restrict__ ew,
                       const int* __restrict__ offs, const int* __restrict__ pos,
                       int* __restrict__ esrc, float* __restrict__ eww, int E,
                       const int* __restrict__ flagp) {
    int e = blockIdx.x * blockDim.x + threadIdx.x;
    if (e >= E) return;
    int flag = *flagp;
    int s = edge_src(ei, e, E, flag);
    int d = edge_dst(ei, e, E, flag);
    int idx = offs[d] + pos[e];
    esrc[idx] = s;
    eww[idx] = ew[e];
}

// ---------------------------------------------------------------------------
// K4b: per-dst degree from CSR segment (sequential, no atomics) -> dinv, minv.
__global__ void k_degcsr(const float* __restrict__ eww, const int* __restrict__ offs,
                         float* __restrict__ dinv, float* __restrict__ minv, int N) {
    int n = blockIdx.x * blockDim.x + threadIdx.x;
    if (n >= N) return;
    int beg = offs[n], end = offs[n + 1];
    float dg = 0.f;
    for (int e = beg; e < end; e++) dg += eww[e];
    dinv[n] = dg > 0.f ? rsqrtf(fmaxf(dg, 1e-30f)) : 0.f;
    minv[n] = 1.f / fmaxf((float)(end - beg), 1.f);
}

// ---------------------------------------------------------------------------
// K5: gather per dst (1 wave/dst), 8-deep unroll for MLP (deg avg ~16);
// edge metadata wave-uniform (readfirstlane'd d) -> scalar loads.
__global__ __launch_bounds__(256) void k_gather(
    const int* __restrict__ esrc, const float* __restrict__ eww,
    const unsigned short* __restrict__ xhbf, const int* __restrict__ offs,
    const float* __restrict__ dinv, const float* __restrict__ minv,
    unsigned short* __restrict__ meanbf, unsigned short* __restrict__ propbf, int N) {
    int lane = threadIdx.x & 63;
    int d = __builtin_amdgcn_readfirstlane(blockIdx.x * 4 + (threadIdx.x >> 6));
    if (d >= N) return;
    int beg = offs[d], end = offs[d + 1];
    bool act = lane < 48;
    int col = 2 * lane;
    float s0 = 0.f, s1 = 0.f, a0 = 0.f, a1 = 0.f;
    int e = beg;
    for (; e + 8 <= end; e += 8) {
        int idx[8]; float wgt[8], dv[8]; unsigned v[8];
#pragma unroll
        for (int q = 0; q < 8; q++) { idx[q] = esrc[e + q]; wgt[q] = eww[e + q]; }
#pragma unroll
        for (int q = 0; q < 8; q++) dv[q] = dinv[idx[q]];
#pragma unroll
        for (int q = 0; q < 8; q++)
            v[q] = act ? *(const unsigned*)(xhbf + (size_t)idx[q] * 96 + col) : 0u;
#pragma unroll
        for (int q = 0; q < 8; q++) {
            float x0 = bf2f((unsigned short)(v[q] & 0xffff));
            float x1 = bf2f((unsigned short)(v[q] >> 16));
            float w2 = wgt[q], dw = dv[q] * w2;
            s0 += w2 * x0; s1 += w2 * x1;
            a0 += dw * x0; a1 += dw * x1;
        }
    }
    for (; e + 4 <= end; e += 4) {
        int idx[4]; float wgt[4], dv[4]; unsigned v[4];
#pragma unroll
        for (int q = 0; q < 4; q++) { idx[q] = esrc[e + q]; wgt[q] = eww[e + q]; }
#pragma unroll
        for (int q = 0; q < 4; q++) dv[q] = dinv[idx[q]];
#pragma unroll
        for (int q = 0; q < 4; q++)
            v[q] = act ? *(const unsigned*)(xhbf + (size_t)idx[q] * 96 + col) : 0u;
#pragma unroll
        for (int q = 0; q < 4; q++) {
            float x0 = bf2f((unsigned short)(v[q] & 0xffff));
            float x1 = bf2f((unsigned short)(v[q] >> 16));
            float w2 = wgt[q], dw = dv[q] * w2;
            s0 += w2 * x0; s1 += w2 * x1;
            a0 += dw * x0; a1 += dw * x1;
        }
    }
    for (; e < end; e++) {
        int s = esrc[e];
        float w2 = eww[e];
        float ds = dinv[s];
        if (act) {
            unsigned v = *(const unsigned*)(xhbf + (size_t)s * 96 + col);
            float x0 = bf2f((unsigned short)(v & 0xffff));
            float x1 = bf2f((unsigned short)(v >> 16));
            s0 += w2 * x0; s1 += w2 * x1;
            a0 += ds * w2 * x0; a1 += ds * w2 * x1;
        }
    }
    if (act) {
        float mi = minv[d], di = dinv[d];
        unsigned mo = (unsigned)f2bf(s0 * mi) | ((unsigned)f2bf(s1 * mi) << 16);
        unsigned po = (unsigned)f2bf(a0 * di) | ((unsigned)f2bf(a1 * di) << 16);
        *(unsigned*)(meanbf + (size_t)d * 96 + col) = mo;
        *(unsigned*)(propbf + (size_t)d * 96 + col) = po;
    }
}

// ---------------------------------------------------------------------------
// K6: epilogue via two K=192 MFMA GEMMs (see R3). 64 nodes/block.
__global__ __launch_bounds__(256) void k_out(
    const unsigned short* __restrict__ meanbf, const unsigned short* __restrict__ propbf,
    const unsigned short* __restrict__ xhbf, const unsigned short* __restrict__ Wf_s,
    const unsigned short* __restrict__ Wf_a, const float* __restrict__ bl,
    const float* __restrict__ ba, float* __restrict__ out, int N) {
    __shared__ unsigned short A[3][64][104];  // 104 shorts = 13x16B (odd) => 2-way max
    int t = threadIdx.x;
    int nb = blockIdx.x * 64;
    for (int u = t; u < 2304; u += 256) {
        int arr = u / 768, rem = u - arr * 768;
        int row = rem / 12, c = rem - row * 12;
        long gn = nb + row;
        const unsigned short* src = (arr == 0) ? meanbf : (arr == 1) ? propbf : xhbf;
        float4 v = (gn < N) ? *(const float4*)(src + gn * 96 + c * 8)
                            : make_float4(0.f, 0.f, 0.f, 0.f);
        *(float4*)&A[arr][row][c * 8] = v;
    }
    __syncthreads();
    int lane = t & 63, w = t >> 6;
    int lr = lane & 15, lg = lane >> 4;
    bf16x8 am[3], ap[3], ax[3];
#pragma unroll
    for (int ks = 0; ks < 3; ks++) {
        int row = w * 16 + lr, kc = ks * 32 + lg * 8;
        am[ks] = *(const bf16x8*)&A[0][row][kc];
        ap[ks] = *(const bf16x8*)&A[1][row][kc];
        ax[ks] = *(const bf16x8*)&A[2][row][kc];
    }
    for (int jt = 0; jt < 8; jt++) {
        f32x4 accS = {0.f, 0.f, 0.f, 0.f};
        f32x4 accA = {0.f, 0.f, 0.f, 0.f};
#pragma unroll
        for (int ks = 0; ks < 3; ks++) {
            size_t boffS = ((size_t)(ks * 4 + lg) * 128 + jt * 16 + lr) * 8;
            size_t boffS2 = ((size_t)((ks + 3) * 4 + lg) * 128 + jt * 16 + lr) * 8;
            bf16x8 b0 = *(const bf16x8*)(Wf_s + boffS);
            bf16x8 b1 = *(const bf16x8*)(Wf_s + boffS2);
            bf16x8 b2 = *(const bf16x8*)(Wf_a + boffS);
            bf16x8 b3 = *(const bf16x8*)(Wf_a + boffS2);
            accS = __builtin_amdgcn_mfma_f32_16x16x32_bf16(am[ks], b0, accS, 0, 0, 0);
            accS = __builtin_amdgcn_mfma_f32_16x16x32_bf16(ax[ks], b1, accS, 0, 0, 0);
            accA = __builtin_amdgcn_mfma_f32_16x16x32_bf16(ap[ks], b2, accA, 0, 0, 0);
            accA = __builtin_amdgcn_mfma_f32_16x16x32_bf16(ax[ks], b3, accA, 0, 0, 0);
        }
        int j = jt * 16 + lr;
        float blj = bl[j], baj = ba[j];
#pragma unroll
        for (int r = 0; r < 4; r++) {
            long n = nb + w * 16 + lg * 4 + r;
            if (n < N) {
                float os = accS[r] + blj;
                float oa = fmaxf(accA[r] + baj, 0.f);
                float o1 = os > 0.f ? os : 0.01f * os;
                float o2 = oa > 0.f ? oa : 0.01f * oa;
                out[n * 128 + j] = fmaxf(o1 + o2, 0.f);
            }
        }
    }
}

// ---------------------------------------------------------------------------
extern "C" void kernel_launch(void* const* d_in, const int* in_sizes, int n_in,
                              void* d_out, int out_size, void* d_ws, size_t ws_size,
                              hipStream_t stream) {
    const float* x    = (const float*)d_in[1];
    const int*   ei   = (const int*)d_in[2];
    const float* ew   = (const float*)d_in[3];
    const float* preW = (const float*)d_in[4];
    const float* preb = (const float*)d_in[5];
    const float* Wl   = (const float*)d_in[6];
    const float* bl   = (const float*)d_in[7];
    const float* Wr   = (const float*)d_in[8];
    const float* Wa   = (const float*)d_in[9];
    const float* Va   = (const float*)d_in[10];
    const float* ba   = (const float*)d_in[11];

    const int N = in_sizes[1] / 128;
    const int E = in_sizes[3];
    const int NB = (N + 255) / 256;

    // ws layout
    char* w = (char*)d_ws;
    unsigned short* xhbf   = (unsigned short*)w; w += (size_t)N * 96 * 2;
    unsigned short* meanbf = (unsigned short*)w; w += (size_t)N * 96 * 2;
    unsigned short* propbf = (unsigned short*)w; w += (size_t)N * 96 * 2;
    unsigned short* Wf_s   = (unsigned short*)w; w += (size_t)6 * 4 * 128 * 8 * 2;
    unsigned short* Wf_a   = (unsigned short*)w; w += (size_t)6 * 4 * 128 * 8 * 2;
    unsigned short* Wfp    = (unsigned short*)w; w += (size_t)4 * 4 * 96 * 8 * 2;
    int*   esrc = (int*)w;   w += (size_t)E * 4;
    float* eww  = (float*)w; w += (size_t)E * 4;
    int*   pos  = (int*)w;   w += (size_t)E * 4;
    int*   cnt_i = (int*)w;  w += (size_t)N * 4;
    float* dinv = (float*)w; w += (size_t)N * 4;
    float* minv = (float*)w; w += (size_t)N * 4;
    int*   offs = (int*)w;   w += (size_t)(N + 1) * 4;
    int*   bsum = (int*)w;   w += 256 * 4;
    int*   flag = (int*)w;

    const int nz4 = (N + 3) / 4;  // int4 chunks to zero (may overrun into dinv:
                                  // harmless, dinv fully rewritten by k_degcsr)
    const int wprep_blocks = (8192 + nz4 + 255) / 256;

    k_flag<<<1, 1024, 0, stream>>>((const unsigned*)ei, flag);
    k_wprep<<<wprep_blocks, 256, 0, stream>>>(Wl, Wr, Wa, Va, preW, Wf_s, Wf_a, Wfp,
                                              (int4*)cnt_i, nz4);
    k_xh<<<(N + 63) / 64, 256, 0, stream>>>(x, Wfp, preb, xhbf, (float*)d_out, N);
    k_count<<<(E + 255) / 256, 256, 0, stream>>>(ei, cnt_i, pos, E, flag);
    k_scan_blk<<<NB, 256, 0, stream>>>(cnt_i, offs, bsum, N);
    k_scan_top<<<1, 256, 0, stream>>>(bsum, NB);
    k_scan_add<<<NB, 256, 0, stream>>>(offs, bsum, N);
    k_fill<<<(E + 255) / 256, 256, 0, stream>>>(ei, ew, offs, pos, esrc, eww, E, flag);
    k_degcsr<<<NB, 256, 0, stream>>>(eww, offs, dinv, minv, N);
    k_gather<<<(N + 3) / 4, 256, 0, stream>>>(esrc, eww, xhbf, offs, dinv,
                                              minv, meanbf, propbf, N);
    k_out<<<(N + 63) / 64, 256, 0, stream>>>(meanbf, propbf, xhbf, Wf_s, Wf_a,
                                             bl, ba, (float*)d_out + (size_t)N * 128, N);
}

// Round 8
// 147.467 us; speedup vs baseline: 9.0733x; 1.0934x over previous
//
#include <hip/hip_runtime.h>

// N=50000, E=800000, CUR=128, HID=96, OUT=128 (derived at runtime)

typedef __attribute__((ext_vector_type(8))) short bf16x8;   // MFMA A/B frag
typedef __attribute__((ext_vector_type(4))) float f32x4;    // MFMA C/D frag

// ---------------------------------------------------------------------------
__device__ __forceinline__ float bf2f(unsigned short u) {
    return __uint_as_float(((unsigned)u) << 16);
}
__device__ __forceinline__ unsigned short f2bf(float f) {
    unsigned u = __float_as_uint(f);
    return (unsigned short)((u + 0x7FFFu + ((u >> 16) & 1u)) >> 16);
}

__device__ __forceinline__ int edge_src(const int* ei, int e, int E, int flag) {
    return flag ? ei[2 * e] : ei[e];
}
__device__ __forceinline__ int edge_dst(const int* ei, int e, int E, int flag) {
    return flag ? ei[2 * (E + e)] : ei[E + e];
}

// ---------------------------------------------------------------------------
// K-prep: block 0 = int64/int32 flag detect; blocks 1.. = weight repack into
// MFMA-B-fragment layout + zero the 8-way sharded cnt array (int4 stores).
__global__ void k_wprep(const unsigned* __restrict__ eiu,
                        const float* __restrict__ Wl, const float* __restrict__ Wr,
                        const float* __restrict__ Wa, const float* __restrict__ Va,
                        const float* __restrict__ preW,
                        unsigned short* __restrict__ Wf_s,
                        unsigned short* __restrict__ Wf_a,
                        unsigned short* __restrict__ Wfp,
                        int* __restrict__ flag,
                        int4* __restrict__ cnt4, int nz4) {
    if (blockIdx.x == 0) {  // flag: high words of first 1024 row-0 entries
        __shared__ int bad;
        if (threadIdx.x == 0) bad = 0;
        __syncthreads();
        int nb = 0;
#pragma unroll
        for (int q = 0; q < 4; q++) {
            unsigned w = eiu[2 * (threadIdx.x * 4 + q) + 1];
            if (w != 0) nb++;
        }
        if (nb) atomicAdd(&bad, nb);
        __syncthreads();
        if (threadIdx.x == 0) *flag = (bad == 0) ? 1 : 0;  // 1 => int64
        return;
    }
    int tid = (blockIdx.x - 1) * blockDim.x + threadIdx.x;
    if (tid < 6144) {  // main weights: 2 mats x 6 ksteps x 4 g x 128 j
        int mat = tid / 3072, rem = tid % 3072;
        int kstep = rem / 512, rem2 = rem % 512;
        int g = rem2 / 128, j = rem2 % 128;
        int k0 = kstep * 32 + g * 8;
        const float* Wtop = mat ? Wa : Wl;
        const float* Wbot = mat ? Va : Wr;
        unsigned short* dst = (mat ? Wf_a : Wf_s) + (((size_t)(kstep * 4 + g) * 128 + j) * 8);
#pragma unroll
        for (int kk = 0; kk < 8; kk++) {
            int k = k0 + kk;
            float v = (k < 96) ? Wtop[k * 128 + j] : Wbot[(k - 96) * 128 + j];
            dst[kk] = f2bf(v);
        }
    } else if (tid < 7680) {  // pre weights: 4 ksteps x 4 g x 96 j
        int rem = tid - 6144;
        int kstep = rem / 384, rem2 = rem % 384;
        int g = rem2 / 96, j = rem2 % 96;
        int k0 = kstep * 32 + g * 8;
        unsigned short* dst = Wfp + (((size_t)(kstep * 4 + g) * 96 + j) * 8);
#pragma unroll
        for (int kk = 0; kk < 8; kk++) dst[kk] = f2bf(preW[(k0 + kk) * 96 + j]);
    } else if (tid >= 8192 && tid < 8192 + nz4) {  // zero cntS (8N ints)
        cnt4[tid - 8192] = make_int4(0, 0, 0, 0);
    }
}

// ---------------------------------------------------------------------------
// K1: MERGED. Blocks [0,xhBlocks): xh = x @ pre_W + pre_b (MFMA) + his=x copy.
// Blocks [xhBlocks, ...): edge rank/count with 8-way sharded atomics
// (shard = blockIdx&7 ~ XCD -> atomics stay XCD-local). Independent work;
// atomic-latency blocks co-schedule with MFMA blocks (separate pipes).
__global__ __launch_bounds__(256) void k_xh_count(
    const float* __restrict__ x, const unsigned short* __restrict__ Wfp,
    const float* __restrict__ b, unsigned short* __restrict__ xhbf,
    float* __restrict__ out0, int N, int xhBlocks,
    const int* __restrict__ ei, int* __restrict__ cntS, int* __restrict__ pos,
    int E, const int* __restrict__ flagp) {
    __shared__ unsigned short X[64][136];  // 136 shorts = 17x16B (odd) => 2-way max
    if (blockIdx.x >= xhBlocks) {  // ---- count part ----
        int e = (blockIdx.x - xhBlocks) * 256 + threadIdx.x;
        if (e < E) {
            int flag = *flagp;
            int d = edge_dst(ei, e, E, flag);
            int shard = blockIdx.x & 7;
            int lp = atomicAdd(&cntS[(size_t)shard * N + d], 1);
            pos[e] = (lp << 3) | shard;
        }
        return;
    }
    // ---- xh part ----
    int t = threadIdx.x;
    int nb = blockIdx.x * 64;
    for (int u = t; u < 2048; u += 256) {
        int row = u >> 5, q = u & 31;
        long gn = nb + row;
        float4 v = make_float4(0.f, 0.f, 0.f, 0.f);
        if (gn < N) {
            v = ((const float4*)(x + gn * 128))[q];
            ((float4*)(out0 + gn * 128))[q] = v;  // his = x
        }
        unsigned short* p = &X[row][q * 4];
        p[0] = f2bf(v.x); p[1] = f2bf(v.y); p[2] = f2bf(v.z); p[3] = f2bf(v.w);
    }
    __syncthreads();
    int lane = t & 63, w = t >> 6;
    int lr = lane & 15, lg = lane >> 4;
    bf16x8 a[4];
#pragma unroll
    for (int ks = 0; ks < 4; ks++)
        a[ks] = *(const bf16x8*)&X[w * 16 + lr][ks * 32 + lg * 8];
    for (int jt = 0; jt < 6; jt++) {
        f32x4 acc = {0.f, 0.f, 0.f, 0.f};
#pragma unroll
        for (int ks = 0; ks < 4; ks++) {
            bf16x8 bf = *(const bf16x8*)(Wfp + (((size_t)(ks * 4 + lg) * 96 + jt * 16 + lr) * 8));
            acc = __builtin_amdgcn_mfma_f32_16x16x32_bf16(a[ks], bf, acc, 0, 0, 0);
        }
        int h = jt * 16 + lr;
        float bb = b[h];
#pragma unroll
        for (int r = 0; r < 4; r++) {
            long n = nb + w * 16 + lg * 4 + r;
            if (n < N) xhbf[n * 96 + h] = f2bf(acc[r] + bb);
        }
    }
}

// ---------------------------------------------------------------------------
// Prefix scan over per-node totals (sum of 8 shards); also writes per-node
// shard-exclusive-prefix sdelta[s][n] so fill can reconstruct global rank.
__global__ void k_scan_blk(const int* __restrict__ cntS, int* __restrict__ sdelta,
                           int* __restrict__ offs, int* __restrict__ bsum, int N) {
    __shared__ int sh[256];
    int t = threadIdx.x;
    int n = blockIdx.x * 256 + t;
    int total = 0;
    if (n < N) {
        int run = 0;
#pragma unroll
        for (int s = 0; s < 8; s++) {
            sdelta[(size_t)s * N + n] = run;
            run += cntS[(size_t)s * N + n];
        }
        total = run;
    }
    sh[t] = total;
    __syncthreads();
    for (int off = 1; off < 256; off <<= 1) {
        int add = (t >= off) ? sh[t - off] : 0;
        __syncthreads();
        sh[t] += add;
        __syncthreads();
    }
    if (n < N) offs[n + 1] = sh[t];
    if (t == 255) bsum[blockIdx.x] = sh[255];
    if (blockIdx.x == 0 && t == 0) offs[0] = 0;
}

__global__ void k_scan_top(int* __restrict__ bsum, int nb) {
    __shared__ int sh[256];
    int t = threadIdx.x;
    sh[t] = (t < nb) ? bsum[t] : 0;
    __syncthreads();
    for (int off = 1; off < 256; off <<= 1) {
        int add = (t >= off) ? sh[t - off] : 0;
        __syncthreads();
        sh[t] += add;
        __syncthreads();
    }
    bsum[t] = sh[t];
}

__global__ void k_scan_add(int* __restrict__ offs, const int* __restrict__ bsum, int N) {
    int t = threadIdx.x;
    int n = blockIdx.x * 256 + t;
    if (n < N && blockIdx.x > 0) offs[n + 1] += bsum[blockIdx.x - 1];
}

// ---------------------------------------------------------------------------
// K4: fill CSR, no atomics: idx = offs[d] + sdelta[shard][d] + localpos.
__global__ void k_fill(const int* __restrict__ ei, const float* __restrict__ ew,
                       const int* __restrict__ offs, const int* __restrict__ sdelta,
                       const int* __restrict__ pos, int* __restrict__ esrc,
                       float* __restrict__ eww, int E, int N,
                       const int* __restrict__ flagp) {
    int e = blockIdx.x * blockDim.x + threadIdx.x;
    if (e >= E) return;
    int flag = *flagp;
    int s = edge_src(ei, e, E, flag);
    int d = edge_dst(ei, e, E, flag);
    int pp = pos[e];
    int shard = pp & 7, lp = pp >> 3;
    int idx = offs[d] + sdelta[(size_t)shard * N + d] + lp;
    esrc[idx] = s;
    eww[idx] = ew[e];
}

// ---------------------------------------------------------------------------
// K4b: per-dst degree from CSR segment -> dinv, minv.
__global__ void k_degcsr(const float* __restrict__ eww, const int* __restrict__ offs,
                         float* __restrict__ dinv, float* __restrict__ minv, int N) {
    int n = blockIdx.x * blockDim.x + threadIdx.x;
    if (n >= N) return;
    int beg = offs[n], end = offs[n + 1];
    float dg = 0.f;
    for (int e = beg; e < end; e++) dg += eww[e];
    dinv[n] = dg > 0.f ? rsqrtf(fmaxf(dg, 1e-30f)) : 0.f;
    minv[n] = 1.f / fmaxf((float)(end - beg), 1.f);
}

// ---------------------------------------------------------------------------
// K5: gather per dst (1 wave/dst), 8-deep unroll for MLP.
__global__ __launch_bounds__(256) void k_gather(
    const int* __restrict__ esrc, const float* __restrict__ eww,
    const unsigned short* __restrict__ xhbf, const int* __restrict__ offs,
    const float* __restrict__ dinv, const float* __restrict__ minv,
    unsigned short* __restrict__ meanbf, unsigned short* __restrict__ propbf, int N) {
    int lane = threadIdx.x & 63;
    int d = __builtin_amdgcn_readfirstlane(blockIdx.x * 4 + (threadIdx.x >> 6));
    if (d >= N) return;
    int beg = offs[d], end = offs[d + 1];
    bool act = lane < 48;
    int col = 2 * lane;
    float s0 = 0.f, s1 = 0.f, a0 = 0.f, a1 = 0.f;
    int e = beg;
    for (; e + 8 <= end; e += 8) {
        int idx[8]; float wgt[8], dv[8]; unsigned v[8];
#pragma unroll
        for (int q = 0; q < 8; q++) { idx[q] = esrc[e + q]; wgt[q] = eww[e + q]; }
#pragma unroll
        for (int q = 0; q < 8; q++) dv[q] = dinv[idx[q]];
#pragma unroll
        for (int q = 0; q < 8; q++)
            v[q] = act ? *(const unsigned*)(xhbf + (size_t)idx[q] * 96 + col) : 0u;
#pragma unroll
        for (int q = 0; q < 8; q++) {
            float x0 = bf2f((unsigned short)(v[q] & 0xffff));
            float x1 = bf2f((unsigned short)(v[q] >> 16));
            float w2 = wgt[q], dw = dv[q] * w2;
            s0 += w2 * x0; s1 += w2 * x1;
            a0 += dw * x0; a1 += dw * x1;
        }
    }
    for (; e + 4 <= end; e += 4) {
        int idx[4]; float wgt[4], dv[4]; unsigned v[4];
#pragma unroll
        for (int q = 0; q < 4; q++) { idx[q] = esrc[e + q]; wgt[q] = eww[e + q]; }
#pragma unroll
        for (int q = 0; q < 4; q++) dv[q] = dinv[idx[q]];
#pragma unroll
        for (int q = 0; q < 4; q++)
            v[q] = act ? *(const unsigned*)(xhbf + (size_t)idx[q] * 96 + col) : 0u;
#pragma unroll
        for (int q = 0; q < 4; q++) {
            float x0 = bf2f((unsigned short)(v[q] & 0xffff));
            float x1 = bf2f((unsigned short)(v[q] >> 16));
            float w2 = wgt[q], dw = dv[q] * w2;
            s0 += w2 * x0; s1 += w2 * x1;
            a0 += dw * x0; a1 += dw * x1;
        }
    }
    for (; e < end; e++) {
        int s = esrc[e];
        float w2 = eww[e];
        float ds = dinv[s];
        if (act) {
            unsigned v = *(const unsigned*)(xhbf + (size_t)s * 96 + col);
            float x0 = bf2f((unsigned short)(v & 0xffff));
            float x1 = bf2f((unsigned short)(v >> 16));
            s0 += w2 * x0; s1 += w2 * x1;
            a0 += ds * w2 * x0; a1 += ds * w2 * x1;
        }
    }
    if (act) {
        float mi = minv[d], di = dinv[d];
        unsigned mo = (unsigned)f2bf(s0 * mi) | ((unsigned)f2bf(s1 * mi) << 16);
        unsigned po = (unsigned)f2bf(a0 * di) | ((unsigned)f2bf(a1 * di) << 16);
        *(unsigned*)(meanbf + (size_t)d * 96 + col) = mo;
        *(unsigned*)(propbf + (size_t)d * 96 + col) = po;
    }
}

// ---------------------------------------------------------------------------
// K6: epilogue via two K=192 MFMA GEMMs (see R3). 64 nodes/block.
__global__ __launch_bounds__(256) void k_out(
    const unsigned short* __restrict__ meanbf, const unsigned short* __restrict__ propbf,
    const unsigned short* __restrict__ xhbf, const unsigned short* __restrict__ Wf_s,
    const unsigned short* __restrict__ Wf_a, const float* __restrict__ bl,
    const float* __restrict__ ba, float* __restrict__ out, int N) {
    __shared__ unsigned short A[3][64][104];  // 104 shorts = 13x16B (odd) => 2-way max
    int t = threadIdx.x;
    int nb = blockIdx.x * 64;
    for (int u = t; u < 2304; u += 256) {
        int arr = u / 768, rem = u - arr * 768;
        int row = rem / 12, c = rem - row * 12;
        long gn = nb + row;
        const unsigned short* src = (arr == 0) ? meanbf : (arr == 1) ? propbf : xhbf;
        float4 v = (gn < N) ? *(const float4*)(src + gn * 96 + c * 8)
                            : make_float4(0.f, 0.f, 0.f, 0.f);
        *(float4*)&A[arr][row][c * 8] = v;
    }
    __syncthreads();
    int lane = t & 63, w = t >> 6;
    int lr = lane & 15, lg = lane >> 4;
    bf16x8 am[3], ap[3], ax[3];
#pragma unroll
    for (int ks = 0; ks < 3; ks++) {
        int row = w * 16 + lr, kc = ks * 32 + lg * 8;
        am[ks] = *(const bf16x8*)&A[0][row][kc];
        ap[ks] = *(const bf16x8*)&A[1][row][kc];
        ax[ks] = *(const bf16x8*)&A[2][row][kc];
    }
    for (int jt = 0; jt < 8; jt++) {
        f32x4 accS = {0.f, 0.f, 0.f, 0.f};
        f32x4 accA = {0.f, 0.f, 0.f, 0.f};
#pragma unroll
        for (int ks = 0; ks < 3; ks++) {
            size_t boffS = ((size_t)(ks * 4 + lg) * 128 + jt * 16 + lr) * 8;
            size_t boffS2 = ((size_t)((ks + 3) * 4 + lg) * 128 + jt * 16 + lr) * 8;
            bf16x8 b0 = *(const bf16x8*)(Wf_s + boffS);
            bf16x8 b1 = *(const bf16x8*)(Wf_s + boffS2);
            bf16x8 b2 = *(const bf16x8*)(Wf_a + boffS);
            bf16x8 b3 = *(const bf16x8*)(Wf_a + boffS2);
            accS = __builtin_amdgcn_mfma_f32_16x16x32_bf16(am[ks], b0, accS, 0, 0, 0);
            accS = __builtin_amdgcn_mfma_f32_16x16x32_bf16(ax[ks], b1, accS, 0, 0, 0);
            accA = __builtin_amdgcn_mfma_f32_16x16x32_bf16(ap[ks], b2, accA, 0, 0, 0);
            accA = __builtin_amdgcn_mfma_f32_16x16x32_bf16(ax[ks], b3, accA, 0, 0, 0);
        }
        int j = jt * 16 + lr;
        float blj = bl[j], baj = ba[j];
#pragma unroll
        for (int r = 0; r < 4; r++) {
            long n = nb + w * 16 + lg * 4 + r;
            if (n < N) {
                float os = accS[r] + blj;
                float oa = fmaxf(accA[r] + baj, 0.f);
                float o1 = os > 0.f ? os : 0.01f * os;
                float o2 = oa > 0.f ? oa : 0.01f * oa;
                out[n * 128 + j] = fmaxf(o1 + o2, 0.f);
            }
        }
    }
}

// ---------------------------------------------------------------------------
extern "C" void kernel_launch(void* const* d_in, const int* in_sizes, int n_in,
                              void* d_out, int out_size, void* d_ws, size_t ws_size,
                              hipStream_t stream) {
    const float* x    = (const float*)d_in[1];
    const int*   ei   = (const int*)d_in[2];
    const float* ew   = (const float*)d_in[3];
    const float* preW = (const float*)d_in[4];
    const float* preb = (const float*)d_in[5];
    const float* Wl   = (const float*)d_in[6];
    const float* bl   = (const float*)d_in[7];
    const float* Wr   = (const float*)d_in[8];
    const float* Wa   = (const float*)d_in[9];
    const float* Va   = (const float*)d_in[10];
    const float* ba   = (const float*)d_in[11];

    const int N = in_sizes[1] / 128;
    const int E = in_sizes[3];
    const int NB = (N + 255) / 256;

    // ws layout
    char* w = (char*)d_ws;
    unsigned short* xhbf   = (unsigned short*)w; w += (size_t)N * 96 * 2;
    unsigned short* meanbf = (unsigned short*)w; w += (size_t)N * 96 * 2;
    unsigned short* propbf = (unsigned short*)w; w += (size_t)N * 96 * 2;
    unsigned short* Wf_s   = (unsigned short*)w; w += (size_t)6 * 4 * 128 * 8 * 2;
    unsigned short* Wf_a   = (unsigned short*)w; w += (size_t)6 * 4 * 128 * 8 * 2;
    unsigned short* Wfp    = (unsigned short*)w; w += (size_t)4 * 4 * 96 * 8 * 2;
    int*   esrc   = (int*)w;   w += (size_t)E * 4;
    float* eww    = (float*)w; w += (size_t)E * 4;
    int*   pos    = (int*)w;   w += (size_t)E * 4;
    int*   cntS   = (int*)w;   w += (size_t)8 * N * 4;  // 8 shards
    int*   sdelta = (int*)w;   w += (size_t)8 * N * 4;  // shard prefix per node
    float* dinv   = (float*)w; w += (size_t)N * 4;
    float* minv   = (float*)w; w += (size_t)N * 4;
    int*   offs   = (int*)w;   w += (size_t)(N + 1) * 4;
    int*   bsum   = (int*)w;   w += 256 * 4;
    int*   flag   = (int*)w;

    const int nz4 = (8 * N + 3) / 4;  // int4 chunks to zero cntS
    const int wprep_blocks = 1 + (8192 + nz4 + 255) / 256;
    const int xhBlocks = (N + 63) / 64;
    const int cntBlocks = (E + 255) / 256;

    k_wprep<<<wprep_blocks, 256, 0, stream>>>((const unsigned*)ei, Wl, Wr, Wa, Va,
                                              preW, Wf_s, Wf_a, Wfp, flag,
                                              (int4*)cntS, nz4);
    k_xh_count<<<xhBlocks + cntBlocks, 256, 0, stream>>>(
        x, Wfp, preb, xhbf, (float*)d_out, N, xhBlocks, ei, cntS, pos, E, flag);
    k_scan_blk<<<NB, 256, 0, stream>>>(cntS, sdelta, offs, bsum, N);
    k_scan_top<<<1, 256, 0, stream>>>(bsum, NB);
    k_scan_add<<<NB, 256, 0, stream>>>(offs, bsum, N);
    k_fill<<<(E + 255) / 256, 256, 0, stream>>>(ei, ew, offs, sdelta, pos, esrc,
                                                eww, E, N, flag);
    k_degcsr<<<NB, 256, 0, stream>>>(eww, offs, dinv, minv, N);
    k_gather<<<(N + 3) / 4, 256, 0, stream>>>(esrc, eww, xhbf, offs, dinv,
                                              minv, meanbf, propbf, N);
    k_out<<<(N + 63) / 64, 256, 0, stream>>>(meanbf, propbf, xhbf, Wf_s, Wf_a,
                                             bl, ba, (float*)d_out + (size_t)N * 128, N);
}